// Round 3
// baseline (719.758 us; speedup 1.0000x reference)
//
#include <hip/hip_runtime.h>

// NetEdge GNN round 9: traffic-cut bundle on top of r8's GEMM structure.
//  - kv packing 8B->4B: p2 needs only key&255 (fine bin) + 24-bit val
//    (E<2^24, src<2^24) -> p1scat writes + p2 reads halved.
//  - srcrow int->ushort (src<50000): p2 C-side writes + k_gath index reads halved.
//  - k_pool fused into layer-2 k_mlp2g (atomicAdd into pooled; x1 never written).
//  - k_gath / k_ea_gather: prefetch next chunk's srcrow/eid before the
//    dependent gathers (hides index-load latency on multi-chunk nodes).
// r8 post-mortem: DS-pipe theory confirmed (872->657). All kernels now under
// the ~120us harness poison fills; this round shaves build+fusion overhead.

namespace {
constexpr int N  = 50000;    // nodes
constexpr int E  = 1600000;  // edges
constexpr int G  = 256;      // graphs
constexpr int EC = 32;       // edge channels
constexpr int H  = 64;       // hidden / node channels
constexpr int OUTC = 10;     // classes
constexpr int NB = (N + 255) / 256;   // 196 coarse buckets (node >> 8)
constexpr int CHUNK = 4096;           // edges per pass-1 block
}

// ---- pass 1a: coarse histograms ----
__global__ __launch_bounds__(256) void k_p1hist(const int* __restrict__ row,
                                                const int* __restrict__ col,
                                                int* __restrict__ cntR,
                                                int* __restrict__ cntC) {
    __shared__ int hR[NB], hC[NB];
    for (int i = threadIdx.x; i < NB; i += 256) { hR[i] = 0; hC[i] = 0; }
    __syncthreads();
    int base = blockIdx.x * CHUNK;
    int end = min(base + CHUNK, E);
    for (int e = base + threadIdx.x; e < end; e += 256) {
        atomicAdd(&hR[row[e] >> 8], 1);
        atomicAdd(&hC[col[e] >> 8], 1);
    }
    __syncthreads();
    for (int i = threadIdx.x; i < NB; i += 256) {
        if (hR[i]) atomicAdd(&cntR[i], hR[i]);
        if (hC[i]) atomicAdd(&cntC[i], hC[i]);
    }
}

// ---- pass 1b: scan bucket counts -> bases + cursors; off[N]=E ----
__global__ __launch_bounds__(256) void k_bscan(const int* __restrict__ cntR,
                                               const int* __restrict__ cntC,
                                               int* __restrict__ baseR, int* __restrict__ baseC,
                                               int* __restrict__ curR,  int* __restrict__ curC,
                                               int* __restrict__ offR,  int* __restrict__ offC) {
    __shared__ int sR[256], sC[256];
    int t = threadIdx.x;
    sR[t] = (t < NB) ? cntR[t] : 0;
    sC[t] = (t < NB) ? cntC[t] : 0;
    __syncthreads();
    for (int d = 1; d < 256; d <<= 1) {
        int vR = sR[t], vC = sC[t];
        int uR = (t >= d) ? sR[t - d] : 0;
        int uC = (t >= d) ? sC[t - d] : 0;
        __syncthreads();
        sR[t] = vR + uR; sC[t] = vC + uC;
        __syncthreads();
    }
    if (t < NB) {
        int bR = (t == 0) ? 0 : sR[t - 1];
        int bC = (t == 0) ? 0 : sC[t - 1];
        baseR[t] = bR; curR[t] = bR;
        baseC[t] = bC; curC[t] = bC;
    }
    if (t == 0) { offR[N] = E; offC[N] = E; }
}

// ---- pass 1c: coarse scatter of packed ((key&255)<<24 | val), 4B ----
__global__ __launch_bounds__(256) void k_p1scat(const int* __restrict__ row,
                                                const int* __restrict__ col,
                                                int* __restrict__ curR, int* __restrict__ curC,
                                                unsigned* __restrict__ kvR,
                                                unsigned* __restrict__ kvC) {
    __shared__ int hR[NB], hC[NB];
    __shared__ int cR[NB], cC[NB];
    for (int i = threadIdx.x; i < NB; i += 256) { hR[i] = 0; hC[i] = 0; }
    __syncthreads();
    int base = blockIdx.x * CHUNK;
    int end = min(base + CHUNK, E);
    for (int e = base + threadIdx.x; e < end; e += 256) {
        atomicAdd(&hR[row[e] >> 8], 1);
        atomicAdd(&hC[col[e] >> 8], 1);
    }
    __syncthreads();
    for (int i = threadIdx.x; i < NB; i += 256) {
        cR[i] = hR[i] ? atomicAdd(&curR[i], hR[i]) : 0;
        cC[i] = hC[i] ? atomicAdd(&curC[i], hC[i]) : 0;
    }
    __syncthreads();
    for (int e = base + threadIdx.x; e < end; e += 256) {
        int r = row[e], c = col[e];
        int pR = atomicAdd(&cR[r >> 8], 1);
        kvR[pR] = ((unsigned)(r & 255) << 24) | (unsigned)e;   // e < 2^24
        int pC = atomicAdd(&cC[c >> 8], 1);
        kvC[pC] = ((unsigned)(c & 255) << 24) | (unsigned)r;   // r < 2^24
    }
}

// ---- pass 2: per-bucket fine bin (4B kv; C-side emits ushort srcrow) ----
__global__ __launch_bounds__(256) void k_p2(const unsigned* __restrict__ kvR,
                                            const unsigned* __restrict__ kvC,
                                            const int* __restrict__ baseR, const int* __restrict__ baseC,
                                            const int* __restrict__ cntR,  const int* __restrict__ cntC,
                                            int* __restrict__ offR, int* __restrict__ offC,
                                            int* __restrict__ eid,
                                            unsigned short* __restrict__ srcrow) {
    bool isC = blockIdx.x >= NB;
    int b = isC ? blockIdx.x - NB : blockIdx.x;
    const unsigned* kv = isC ? kvC : kvR;
    int sbase = isC ? baseC[b] : baseR[b];
    int scnt  = isC ? cntC[b]  : cntR[b];
    int* off  = isC ? offC : offR;

    __shared__ int hist[256], s[256], cur[256];
    int t = threadIdx.x;
    hist[t] = 0;
    __syncthreads();
    for (int i = sbase + t; i < sbase + scnt; i += 256) {
        atomicAdd(&hist[kv[i] >> 24], 1);
    }
    __syncthreads();
    s[t] = hist[t];
    __syncthreads();
    for (int d = 1; d < 256; d <<= 1) {
        int v = s[t];
        int u = (t >= d) ? s[t - d] : 0;
        __syncthreads();
        s[t] = v + u;
        __syncthreads();
    }
    int excl = (t == 0) ? 0 : s[t - 1];
    cur[t] = sbase + excl;
    int node = (b << 8) + t;
    if (node < N) off[node] = sbase + excl;
    __syncthreads();
    for (int i = sbase + t; i < sbase + scnt; i += 256) {
        unsigned p = kv[i];
        int lk = p >> 24;
        int pos = atomicAdd(&cur[lk], 1);
        int val = (int)(p & 0xFFFFFFu);
        if (isC) srcrow[pos] = (unsigned short)val;
        else     eid[pos] = val;
    }
}

// ---- ea[n] = sum of edge_attr over outgoing edges; float4, 8 edges/load ----
__global__ __launch_bounds__(256) void k_ea_gather(const float4* __restrict__ ea4_in,
                                                   const int* __restrict__ eid,
                                                   const int* __restrict__ offR,
                                                   float4* __restrict__ ea_out) {
    int n = blockIdx.x * 4 + (threadIdx.x >> 6);
    int lane = threadIdx.x & 63;
    if (n >= N) return;
    int grp = lane >> 3;
    int q   = lane & 7;
    int b = offR[n], e_end = offR[n + 1];
    float4 acc = make_float4(0.f, 0.f, 0.f, 0.f);
    int ev = eid[min(b + lane, e_end - 1)];
    for (int i0 = b; i0 < e_end; i0 += 32) {
        int nn = i0 + 32;
        int ev_n = (nn < e_end) ? eid[min(nn + lane, e_end - 1)] : 0;  // prefetch
        int lim = e_end - i0;
        float4 v[4];
        #pragma unroll
        for (int s = 0; s < 4; ++s) {
            int e = __shfl(ev, s * 8 + grp);
            v[s] = ea4_in[(size_t)e * 8 + q];
        }
        #pragma unroll
        for (int s = 0; s < 4; ++s) {
            if (s * 8 + grp < lim) {
                acc.x += v[s].x; acc.y += v[s].y; acc.z += v[s].z; acc.w += v[s].w;
            }
        }
        ev = ev_n;
    }
    #pragma unroll
    for (int m = 8; m <= 32; m <<= 1) {
        acc.x += __shfl_xor(acc.x, m);
        acc.y += __shfl_xor(acc.y, m);
        acc.z += __shfl_xor(acc.z, m);
        acc.w += __shfl_xor(acc.w, m);
    }
    if (lane < 8) ea_out[(size_t)n * 8 + q] = acc;
}

// ---- k_mlp1g: C[n,0:64]=zrel=[x||ea]@Wz, C[n,64:128]=relu([x||ea]@Wh+bh) ----
// 32-node block, 256 threads, thread tile 2 rows x 8 cols, LDS ~62 KB.
__global__ __launch_bounds__(256) void k_mlp1g(const float* __restrict__ x,
                        const float* __restrict__ ea,
                        const float* __restrict__ Wz, const float* __restrict__ Wh,
                        const float* __restrict__ bh,
                        float* __restrict__ zrel, float* __restrict__ hroot) {
    __shared__ float As[32][100];    // [node][k], 96 padded to 100
    __shared__ float Ws[96][128];    // [k][j]: j<64 -> Wz, j>=64 -> Wh
    int n0 = blockIdx.x * 32;
    int t = threadIdx.x;
    {   // stage x (cols 0..63)
        int c4 = (t & 15) * 4;
        int r0 = t >> 4;
        #pragma unroll
        for (int r = r0; r < 32; r += 16) {
            int n = min(n0 + r, N - 1);
            *(float4*)&As[r][c4] = *(const float4*)&x[(size_t)n * H + c4];
        }
        // stage ea (cols 64..95)
        int c2 = (t & 7) * 4;
        int r1 = t >> 3;             // 0..31
        int n = min(n0 + r1, N - 1);
        *(float4*)&As[r1][64 + c2] = *(const float4*)&ea[(size_t)n * EC + c2];
    }
    for (int i = t; i < 96 * 128; i += 256) {
        int k = i >> 7, j = i & 127;
        Ws[k][j] = (j < 64) ? Wz[k * 64 + j] : Wh[k * 64 + (j - 64)];
    }
    __syncthreads();
    int tr = t >> 4;                 // rows tr*2 .. tr*2+1
    int tc = t & 15;                 // cols tc*8 .. tc*8+7
    float acc[2][8];
    #pragma unroll
    for (int i = 0; i < 2; ++i)
        #pragma unroll
        for (int j = 0; j < 8; ++j) acc[i][j] = 0.f;
    #pragma unroll 2
    for (int k = 0; k < 96; k += 4) {
        float4 a0 = *(const float4*)&As[tr * 2][k];
        float4 a1 = *(const float4*)&As[tr * 2 + 1][k];
        #pragma unroll
        for (int kk = 0; kk < 4; ++kk) {
            float4 w0 = *(const float4*)&Ws[k + kk][tc * 8];
            float4 w1 = *(const float4*)&Ws[k + kk][tc * 8 + 4];
            float av0 = (kk == 0) ? a0.x : (kk == 1) ? a0.y : (kk == 2) ? a0.z : a0.w;
            float av1 = (kk == 0) ? a1.x : (kk == 1) ? a1.y : (kk == 2) ? a1.z : a1.w;
            acc[0][0] += av0 * w0.x; acc[0][1] += av0 * w0.y;
            acc[0][2] += av0 * w0.z; acc[0][3] += av0 * w0.w;
            acc[0][4] += av0 * w1.x; acc[0][5] += av0 * w1.y;
            acc[0][6] += av0 * w1.z; acc[0][7] += av0 * w1.w;
            acc[1][0] += av1 * w0.x; acc[1][1] += av1 * w0.y;
            acc[1][2] += av1 * w0.z; acc[1][3] += av1 * w0.w;
            acc[1][4] += av1 * w1.x; acc[1][5] += av1 * w1.y;
            acc[1][6] += av1 * w1.z; acc[1][7] += av1 * w1.w;
        }
    }
    if (tc < 8) {                    // zrel cols, no bias, no relu
        int jb = tc * 8;
        #pragma unroll
        for (int i = 0; i < 2; ++i) {
            int n = n0 + tr * 2 + i;
            if (n < N) {
                *(float4*)&zrel[(size_t)n * H + jb] =
                    make_float4(acc[i][0], acc[i][1], acc[i][2], acc[i][3]);
                *(float4*)&zrel[(size_t)n * H + jb + 4] =
                    make_float4(acc[i][4], acc[i][5], acc[i][6], acc[i][7]);
            }
        }
    } else {                         // hroot cols, +bias, relu
        int jb = (tc - 8) * 8;
        float4 b0 = *(const float4*)&bh[jb];
        float4 b1v = *(const float4*)&bh[jb + 4];
        #pragma unroll
        for (int i = 0; i < 2; ++i) {
            int n = n0 + tr * 2 + i;
            if (n < N) {
                *(float4*)&hroot[(size_t)n * H + jb] = make_float4(
                    fmaxf(acc[i][0] + b0.x, 0.f), fmaxf(acc[i][1] + b0.y, 0.f),
                    fmaxf(acc[i][2] + b0.z, 0.f), fmaxf(acc[i][3] + b0.w, 0.f));
                *(float4*)&hroot[(size_t)n * H + jb + 4] = make_float4(
                    fmaxf(acc[i][4] + b1v.x, 0.f), fmaxf(acc[i][5] + b1v.y, 0.f),
                    fmaxf(acc[i][6] + b1v.z, 0.f), fmaxf(acc[i][7] + b1v.w, 0.f));
            }
        }
    }
}

// ---- k_gath: hrel[n] = relu(sum_{e in CSC(n)} zrel[src(e)] + relb1) ----
// wave per node, no LDS (max occupancy), 8 loads in flight + index prefetch.
__global__ __launch_bounds__(256) void k_gath(const float4* __restrict__ z4,
                        const unsigned short* __restrict__ srcrow,
                        const int* __restrict__ offC,
                        const float4* __restrict__ relb1_4,
                        float4* __restrict__ hrel4) {
    int n = blockIdx.x * 4 + (threadIdx.x >> 6);
    if (n >= N) return;
    int lane = threadIdx.x & 63;
    int grp = lane >> 4;   // edge subgroup 0..3
    int q   = lane & 15;   // float4 chunk of the 64-ch row
    int b = offC[n], e_end = offC[n + 1];
    float4 acc = make_float4(0.f, 0.f, 0.f, 0.f);
    int rv = srcrow[min(b + lane, e_end - 1)];
    for (int i0 = b; i0 < e_end; i0 += 32) {
        int nn = i0 + 32;
        int rv_n = (nn < e_end) ? (int)srcrow[min(nn + lane, e_end - 1)] : 0;  // prefetch
        int lim = e_end - i0;
        float4 v[8];
        #pragma unroll
        for (int s = 0; s < 8; ++s) {
            int src = __shfl(rv, s * 4 + grp);
            v[s] = z4[(size_t)src * 16 + q];
        }
        #pragma unroll
        for (int s = 0; s < 8; ++s) {
            if (s * 4 + grp < lim) {
                acc.x += v[s].x; acc.y += v[s].y; acc.z += v[s].z; acc.w += v[s].w;
            }
        }
        rv = rv_n;
    }
    #pragma unroll
    for (int m = 16; m <= 32; m <<= 1) {
        acc.x += __shfl_xor(acc.x, m);
        acc.y += __shfl_xor(acc.y, m);
        acc.z += __shfl_xor(acc.z, m);
        acc.w += __shfl_xor(acc.w, m);
    }
    if (lane < 16) {
        float4 b1 = relb1_4[q];
        float4 h;
        h.x = fmaxf(acc.x + b1.x, 0.f);
        h.y = fmaxf(acc.y + b1.y, 0.f);
        h.z = fmaxf(acc.z + b1.z, 0.f);
        h.w = fmaxf(acc.w + b1.w, 0.f);
        hrel4[(size_t)n * 16 + q] = h;
    }
}

// ---- k_mlp2g: xout = relu([hrel||hroot](Nx128) @ [Wr;Wo](128x64) + br+bo)
//      dopool: atomicAdd result into pooled[batch[n]] instead (x1 skipped) ----
__global__ __launch_bounds__(256) void k_mlp2g(const float* __restrict__ hrel,
                        const float* __restrict__ hroot,
                        const float* __restrict__ Wr, const float* __restrict__ Wo,
                        const float* __restrict__ br, const float* __restrict__ bo,
                        float* __restrict__ xout,
                        const int* __restrict__ batch, float* __restrict__ pooled,
                        int dopool) {
    __shared__ float As[32][132];    // [node][k]: k<64 hrel, k>=64 hroot (pad)
    __shared__ float Ws[128][64];    // [k][j]: k<64 Wr, k>=64 Wo
    int n0 = blockIdx.x * 32;
    int t = threadIdx.x;
    {
        int c4 = (t & 15) * 4;
        int r0 = t >> 4;
        #pragma unroll
        for (int r = r0; r < 32; r += 16) {
            int n = min(n0 + r, N - 1);
            *(float4*)&As[r][c4]      = *(const float4*)&hrel [(size_t)n * H + c4];
            *(float4*)&As[r][64 + c4] = *(const float4*)&hroot[(size_t)n * H + c4];
        }
    }
    for (int i = t; i < 128 * 64; i += 256) {
        int k = i >> 6, j = i & 63;
        Ws[k][j] = (k < 64) ? Wr[k * 64 + j] : Wo[(k - 64) * 64 + j];
    }
    __syncthreads();
    int tr = t >> 4;                 // rows tr*2 .. +1
    int tc = t & 15;                 // cols tc*4 .. +3
    float acc[2][4];
    #pragma unroll
    for (int i = 0; i < 2; ++i)
        #pragma unroll
        for (int j = 0; j < 4; ++j) acc[i][j] = 0.f;
    #pragma unroll 2
    for (int k = 0; k < 128; k += 4) {
        float4 a0 = *(const float4*)&As[tr * 2][k];
        float4 a1 = *(const float4*)&As[tr * 2 + 1][k];
        #pragma unroll
        for (int kk = 0; kk < 4; ++kk) {
            float4 w = *(const float4*)&Ws[k + kk][tc * 4];
            float av0 = (kk == 0) ? a0.x : (kk == 1) ? a0.y : (kk == 2) ? a0.z : a0.w;
            float av1 = (kk == 0) ? a1.x : (kk == 1) ? a1.y : (kk == 2) ? a1.z : a1.w;
            acc[0][0] += av0 * w.x; acc[0][1] += av0 * w.y;
            acc[0][2] += av0 * w.z; acc[0][3] += av0 * w.w;
            acc[1][0] += av1 * w.x; acc[1][1] += av1 * w.y;
            acc[1][2] += av1 * w.z; acc[1][3] += av1 * w.w;
        }
    }
    int jb = tc * 4;
    float4 bj;
    bj.x = br[jb]     + bo[jb];
    bj.y = br[jb + 1] + bo[jb + 1];
    bj.z = br[jb + 2] + bo[jb + 2];
    bj.w = br[jb + 3] + bo[jb + 3];
    #pragma unroll
    for (int i = 0; i < 2; ++i) {
        int n = n0 + tr * 2 + i;
        if (n < N) {
            float4 r = make_float4(
                fmaxf(acc[i][0] + bj.x, 0.f), fmaxf(acc[i][1] + bj.y, 0.f),
                fmaxf(acc[i][2] + bj.z, 0.f), fmaxf(acc[i][3] + bj.w, 0.f));
            if (dopool) {
                int g = batch[n];
                float* p = &pooled[(size_t)g * H + jb];
                atomicAdd(p + 0, r.x);
                atomicAdd(p + 1, r.y);
                atomicAdd(p + 2, r.z);
                atomicAdd(p + 3, r.w);
            } else {
                *(float4*)&xout[(size_t)n * H + jb] = r;
            }
        }
    }
}

// ---- out = relu(pooled @ finW1 + finb1) @ finW2 + finb2 ----
__global__ void k_final(const float* __restrict__ pooled,
                        const float* __restrict__ W1, const float* __restrict__ b1,
                        const float* __restrict__ W2, const float* __restrict__ b2,
                        float* __restrict__ out) {
    __shared__ float h[H];
    int g = blockIdx.x;
    int j = threadIdx.x;
    const float* p = pooled + (size_t)g * H;
    float acc = b1[j];
    #pragma unroll 8
    for (int k = 0; k < H; ++k) acc += p[k] * W1[k * H + j];
    h[j] = fmaxf(acc, 0.f);
    __syncthreads();
    if (j < OUTC) {
        float o = b2[j];
        #pragma unroll 8
        for (int k = 0; k < H; ++k) o += h[k] * W2[k * OUTC + j];
        out[(size_t)g * OUTC + j] = o;
    }
}

extern "C" void kernel_launch(void* const* d_in, const int* in_sizes, int n_in,
                              void* d_out, int out_size, void* d_ws, size_t ws_size,
                              hipStream_t stream) {
    const float* x         = (const float*)d_in[0];
    const float* edge_attr = (const float*)d_in[1];
    const float* P[16];
    for (int i = 0; i < 16; ++i) P[i] = (const float*)d_in[2 + i];
    const float* finW1 = (const float*)d_in[18];
    const float* finb1 = (const float*)d_in[19];
    const float* finW2 = (const float*)d_in[20];
    const float* finb2 = (const float*)d_in[21];
    const int* row   = (const int*)d_in[22];
    const int* col   = row + E;
    const int* batch = (const int*)d_in[23];
    float* out = (float*)d_out;
    (void)ws_size; (void)n_in; (void)in_sizes; (void)out_size;

    // ---- workspace ----
    float* fw = (float*)d_ws;
    float* zrel   = fw;  fw += (size_t)N * H;   // aliased by kvR during build
    float* hroot  = fw;  fw += (size_t)N * H;
    float* x1     = fw;  fw += (size_t)N * H;   // aliased by kvC during build
    float* hrel   = fw;  fw += (size_t)N * H;
    float* ea     = fw;  fw += (size_t)N * EC;
    float* pooled = fw;  fw += (size_t)G * H;
    int* iw = (int*)fw;
    int* cntR   = iw;  iw += NB;
    int* cntC   = iw;  iw += NB;
    int* baseR  = iw;  iw += NB;
    int* baseC  = iw;  iw += NB;
    int* curR   = iw;  iw += NB;
    int* curC   = iw;  iw += NB;
    int* offR   = iw;  iw += N + 1;
    int* offC   = iw;  iw += N + 1;
    int* eid    = iw;  iw += E;
    unsigned short* srcrow = (unsigned short*)iw;  iw += E / 2;
    // 4B kv arrays alias node float arrays (build-only lifetime)
    unsigned* kvR = (unsigned*)zrel;   // E*4B = 6.4MB <= 12.8MB
    unsigned* kvC = (unsigned*)x1;

    // ---- build CSR/CSC ----
    hipMemsetAsync(cntR, 0, 2 * (size_t)NB * sizeof(int), stream);
    hipMemsetAsync(pooled, 0, (size_t)G * H * sizeof(float), stream);
    int p1grid = (E + CHUNK - 1) / CHUNK;
    k_p1hist<<<p1grid, 256, 0, stream>>>(row, col, cntR, cntC);
    k_bscan<<<1, 256, 0, stream>>>(cntR, cntC, baseR, baseC, curR, curC, offR, offC);
    k_p1scat<<<p1grid, 256, 0, stream>>>(row, col, curR, curC, kvR, kvC);
    k_p2<<<2 * NB, 256, 0, stream>>>(kvR, kvC, baseR, baseC, cntR, cntC,
                                     offR, offC, eid, srcrow);

    // ---- shared edge aggregation ----
    k_ea_gather<<<(N + 3) / 4, 256, 0, stream>>>((const float4*)edge_attr, eid, offR,
                                                 (float4*)ea);

    int gmlp = (N + 31) / 32;   // 1563

    // ---- layer 1 ----
    k_mlp1g<<<gmlp, 256, 0, stream>>>(x, ea, P[0], P[4], P[5], zrel, hroot);
    k_gath<<<(N + 3) / 4, 256, 0, stream>>>((const float4*)zrel, srcrow, offC,
                                            (const float4*)P[1], (float4*)hrel);
    k_mlp2g<<<gmlp, 256, 0, stream>>>(hrel, hroot, P[2], P[6], P[3], P[7], x1,
                                      batch, pooled, 0);

    // ---- layer 2 (mlp2 fused with pool) ----
    k_mlp1g<<<gmlp, 256, 0, stream>>>(x1, ea, P[8], P[12], P[13], zrel, hroot);
    k_gath<<<(N + 3) / 4, 256, 0, stream>>>((const float4*)zrel, srcrow, offC,
                                            (const float4*)P[9], (float4*)hrel);
    k_mlp2g<<<gmlp, 256, 0, stream>>>(hrel, hroot, P[10], P[14], P[11], P[15], x1,
                                      batch, pooled, 1);

    // ---- head ----
    k_final<<<G, 64, 0, stream>>>(pooled, finW1, finb1, finW2, finb2, out);
}

// Round 4
// 649.990 us; speedup vs baseline: 1.1073x; 1.1073x over previous
//
#include <hip/hip_runtime.h>

// NetEdge GNN round 10: r8 structure restored (known 657us), keeping ONLY the
// theory-solid traffic cuts from r9:
//   - kv packing 8B->4B ((key&255)<<24 | 24-bit val)
//   - srcrow int->ushort
// Reverted (r9 regression suspects): index-prefetch restructure in the two
// gather kernels (register-lifetime/waitcnt serialization), and the per-node
// atomicAdd pool fusion (3.2M serialized L2 RMWs) -> separate k_pool again.

namespace {
constexpr int N  = 50000;    // nodes
constexpr int E  = 1600000;  // edges
constexpr int G  = 256;      // graphs
constexpr int EC = 32;       // edge channels
constexpr int H  = 64;       // hidden / node channels
constexpr int OUTC = 10;     // classes
constexpr int NB = (N + 255) / 256;   // 196 coarse buckets (node >> 8)
constexpr int CHUNK = 4096;           // edges per pass-1 block
}

// ---- pass 1a: coarse histograms ----
__global__ __launch_bounds__(256) void k_p1hist(const int* __restrict__ row,
                                                const int* __restrict__ col,
                                                int* __restrict__ cntR,
                                                int* __restrict__ cntC) {
    __shared__ int hR[NB], hC[NB];
    for (int i = threadIdx.x; i < NB; i += 256) { hR[i] = 0; hC[i] = 0; }
    __syncthreads();
    int base = blockIdx.x * CHUNK;
    int end = min(base + CHUNK, E);
    for (int e = base + threadIdx.x; e < end; e += 256) {
        atomicAdd(&hR[row[e] >> 8], 1);
        atomicAdd(&hC[col[e] >> 8], 1);
    }
    __syncthreads();
    for (int i = threadIdx.x; i < NB; i += 256) {
        if (hR[i]) atomicAdd(&cntR[i], hR[i]);
        if (hC[i]) atomicAdd(&cntC[i], hC[i]);
    }
}

// ---- pass 1b: scan bucket counts -> bases + cursors; off[N]=E ----
__global__ __launch_bounds__(256) void k_bscan(const int* __restrict__ cntR,
                                               const int* __restrict__ cntC,
                                               int* __restrict__ baseR, int* __restrict__ baseC,
                                               int* __restrict__ curR,  int* __restrict__ curC,
                                               int* __restrict__ offR,  int* __restrict__ offC) {
    __shared__ int sR[256], sC[256];
    int t = threadIdx.x;
    sR[t] = (t < NB) ? cntR[t] : 0;
    sC[t] = (t < NB) ? cntC[t] : 0;
    __syncthreads();
    for (int d = 1; d < 256; d <<= 1) {
        int vR = sR[t], vC = sC[t];
        int uR = (t >= d) ? sR[t - d] : 0;
        int uC = (t >= d) ? sC[t - d] : 0;
        __syncthreads();
        sR[t] = vR + uR; sC[t] = vC + uC;
        __syncthreads();
    }
    if (t < NB) {
        int bR = (t == 0) ? 0 : sR[t - 1];
        int bC = (t == 0) ? 0 : sC[t - 1];
        baseR[t] = bR; curR[t] = bR;
        baseC[t] = bC; curC[t] = bC;
    }
    if (t == 0) { offR[N] = E; offC[N] = E; }
}

// ---- pass 1c: coarse scatter of packed ((key&255)<<24 | val), 4B ----
__global__ __launch_bounds__(256) void k_p1scat(const int* __restrict__ row,
                                                const int* __restrict__ col,
                                                int* __restrict__ curR, int* __restrict__ curC,
                                                unsigned* __restrict__ kvR,
                                                unsigned* __restrict__ kvC) {
    __shared__ int hR[NB], hC[NB];
    __shared__ int cR[NB], cC[NB];
    for (int i = threadIdx.x; i < NB; i += 256) { hR[i] = 0; hC[i] = 0; }
    __syncthreads();
    int base = blockIdx.x * CHUNK;
    int end = min(base + CHUNK, E);
    for (int e = base + threadIdx.x; e < end; e += 256) {
        atomicAdd(&hR[row[e] >> 8], 1);
        atomicAdd(&hC[col[e] >> 8], 1);
    }
    __syncthreads();
    for (int i = threadIdx.x; i < NB; i += 256) {
        cR[i] = hR[i] ? atomicAdd(&curR[i], hR[i]) : 0;
        cC[i] = hC[i] ? atomicAdd(&curC[i], hC[i]) : 0;
    }
    __syncthreads();
    for (int e = base + threadIdx.x; e < end; e += 256) {
        int r = row[e], c = col[e];
        int pR = atomicAdd(&cR[r >> 8], 1);
        kvR[pR] = ((unsigned)(r & 255) << 24) | (unsigned)e;   // e < 2^24
        int pC = atomicAdd(&cC[c >> 8], 1);
        kvC[pC] = ((unsigned)(c & 255) << 24) | (unsigned)r;   // r < 2^24
    }
}

// ---- pass 2: per-bucket fine bin (4B kv; C-side emits ushort srcrow) ----
__global__ __launch_bounds__(256) void k_p2(const unsigned* __restrict__ kvR,
                                            const unsigned* __restrict__ kvC,
                                            const int* __restrict__ baseR, const int* __restrict__ baseC,
                                            const int* __restrict__ cntR,  const int* __restrict__ cntC,
                                            int* __restrict__ offR, int* __restrict__ offC,
                                            int* __restrict__ eid,
                                            unsigned short* __restrict__ srcrow) {
    bool isC = blockIdx.x >= NB;
    int b = isC ? blockIdx.x - NB : blockIdx.x;
    const unsigned* kv = isC ? kvC : kvR;
    int sbase = isC ? baseC[b] : baseR[b];
    int scnt  = isC ? cntC[b]  : cntR[b];
    int* off  = isC ? offC : offR;

    __shared__ int hist[256], s[256], cur[256];
    int t = threadIdx.x;
    hist[t] = 0;
    __syncthreads();
    for (int i = sbase + t; i < sbase + scnt; i += 256) {
        atomicAdd(&hist[kv[i] >> 24], 1);
    }
    __syncthreads();
    s[t] = hist[t];
    __syncthreads();
    for (int d = 1; d < 256; d <<= 1) {
        int v = s[t];
        int u = (t >= d) ? s[t - d] : 0;
        __syncthreads();
        s[t] = v + u;
        __syncthreads();
    }
    int excl = (t == 0) ? 0 : s[t - 1];
    cur[t] = sbase + excl;
    int node = (b << 8) + t;
    if (node < N) off[node] = sbase + excl;
    __syncthreads();
    for (int i = sbase + t; i < sbase + scnt; i += 256) {
        unsigned p = kv[i];
        int lk = p >> 24;
        int pos = atomicAdd(&cur[lk], 1);
        int val = (int)(p & 0xFFFFFFu);
        if (isC) srcrow[pos] = (unsigned short)val;
        else     eid[pos] = val;
    }
}

// ---- ea[n] = sum of edge_attr over outgoing edges; float4, 8 edges/load ----
__global__ __launch_bounds__(256) void k_ea_gather(const float4* __restrict__ ea4_in,
                                                   const int* __restrict__ eid,
                                                   const int* __restrict__ offR,
                                                   float4* __restrict__ ea_out) {
    int n = blockIdx.x * 4 + (threadIdx.x >> 6);
    int lane = threadIdx.x & 63;
    if (n >= N) return;
    int grp = lane >> 3;
    int q   = lane & 7;
    int b = offR[n], e_end = offR[n + 1];
    float4 acc = make_float4(0.f, 0.f, 0.f, 0.f);
    for (int i0 = b; i0 < e_end; i0 += 32) {
        int lim = e_end - i0;
        int ev = eid[min(i0 + lane, e_end - 1)];
        float4 v[4];
        #pragma unroll
        for (int s = 0; s < 4; ++s) {
            int e = __shfl(ev, s * 8 + grp);
            v[s] = ea4_in[(size_t)e * 8 + q];
        }
        #pragma unroll
        for (int s = 0; s < 4; ++s) {
            if (s * 8 + grp < lim) {
                acc.x += v[s].x; acc.y += v[s].y; acc.z += v[s].z; acc.w += v[s].w;
            }
        }
    }
    #pragma unroll
    for (int m = 8; m <= 32; m <<= 1) {
        acc.x += __shfl_xor(acc.x, m);
        acc.y += __shfl_xor(acc.y, m);
        acc.z += __shfl_xor(acc.z, m);
        acc.w += __shfl_xor(acc.w, m);
    }
    if (lane < 8) ea_out[(size_t)n * 8 + q] = acc;
}

// ---- k_mlp1g: C[n,0:64]=zrel=[x||ea]@Wz, C[n,64:128]=relu([x||ea]@Wh+bh) ----
// 32-node block, 256 threads, thread tile 2 rows x 8 cols, LDS ~62 KB.
__global__ __launch_bounds__(256) void k_mlp1g(const float* __restrict__ x,
                        const float* __restrict__ ea,
                        const float* __restrict__ Wz, const float* __restrict__ Wh,
                        const float* __restrict__ bh,
                        float* __restrict__ zrel, float* __restrict__ hroot) {
    __shared__ float As[32][100];    // [node][k], 96 padded to 100
    __shared__ float Ws[96][128];    // [k][j]: j<64 -> Wz, j>=64 -> Wh
    int n0 = blockIdx.x * 32;
    int t = threadIdx.x;
    {   // stage x (cols 0..63)
        int c4 = (t & 15) * 4;
        int r0 = t >> 4;
        #pragma unroll
        for (int r = r0; r < 32; r += 16) {
            int n = min(n0 + r, N - 1);
            *(float4*)&As[r][c4] = *(const float4*)&x[(size_t)n * H + c4];
        }
        // stage ea (cols 64..95)
        int c2 = (t & 7) * 4;
        int r1 = t >> 3;             // 0..31
        int n = min(n0 + r1, N - 1);
        *(float4*)&As[r1][64 + c2] = *(const float4*)&ea[(size_t)n * EC + c2];
    }
    for (int i = t; i < 96 * 128; i += 256) {
        int k = i >> 7, j = i & 127;
        Ws[k][j] = (j < 64) ? Wz[k * 64 + j] : Wh[k * 64 + (j - 64)];
    }
    __syncthreads();
    int tr = t >> 4;                 // rows tr*2 .. tr*2+1
    int tc = t & 15;                 // cols tc*8 .. tc*8+7
    float acc[2][8];
    #pragma unroll
    for (int i = 0; i < 2; ++i)
        #pragma unroll
        for (int j = 0; j < 8; ++j) acc[i][j] = 0.f;
    #pragma unroll 2
    for (int k = 0; k < 96; k += 4) {
        float4 a0 = *(const float4*)&As[tr * 2][k];
        float4 a1 = *(const float4*)&As[tr * 2 + 1][k];
        #pragma unroll
        for (int kk = 0; kk < 4; ++kk) {
            float4 w0 = *(const float4*)&Ws[k + kk][tc * 8];
            float4 w1 = *(const float4*)&Ws[k + kk][tc * 8 + 4];
            float av0 = (kk == 0) ? a0.x : (kk == 1) ? a0.y : (kk == 2) ? a0.z : a0.w;
            float av1 = (kk == 0) ? a1.x : (kk == 1) ? a1.y : (kk == 2) ? a1.z : a1.w;
            acc[0][0] += av0 * w0.x; acc[0][1] += av0 * w0.y;
            acc[0][2] += av0 * w0.z; acc[0][3] += av0 * w0.w;
            acc[0][4] += av0 * w1.x; acc[0][5] += av0 * w1.y;
            acc[0][6] += av0 * w1.z; acc[0][7] += av0 * w1.w;
            acc[1][0] += av1 * w0.x; acc[1][1] += av1 * w0.y;
            acc[1][2] += av1 * w0.z; acc[1][3] += av1 * w0.w;
            acc[1][4] += av1 * w1.x; acc[1][5] += av1 * w1.y;
            acc[1][6] += av1 * w1.z; acc[1][7] += av1 * w1.w;
        }
    }
    if (tc < 8) {                    // zrel cols, no bias, no relu
        int jb = tc * 8;
        #pragma unroll
        for (int i = 0; i < 2; ++i) {
            int n = n0 + tr * 2 + i;
            if (n < N) {
                *(float4*)&zrel[(size_t)n * H + jb] =
                    make_float4(acc[i][0], acc[i][1], acc[i][2], acc[i][3]);
                *(float4*)&zrel[(size_t)n * H + jb + 4] =
                    make_float4(acc[i][4], acc[i][5], acc[i][6], acc[i][7]);
            }
        }
    } else {                         // hroot cols, +bias, relu
        int jb = (tc - 8) * 8;
        float4 b0 = *(const float4*)&bh[jb];
        float4 b1v = *(const float4*)&bh[jb + 4];
        #pragma unroll
        for (int i = 0; i < 2; ++i) {
            int n = n0 + tr * 2 + i;
            if (n < N) {
                *(float4*)&hroot[(size_t)n * H + jb] = make_float4(
                    fmaxf(acc[i][0] + b0.x, 0.f), fmaxf(acc[i][1] + b0.y, 0.f),
                    fmaxf(acc[i][2] + b0.z, 0.f), fmaxf(acc[i][3] + b0.w, 0.f));
                *(float4*)&hroot[(size_t)n * H + jb + 4] = make_float4(
                    fmaxf(acc[i][4] + b1v.x, 0.f), fmaxf(acc[i][5] + b1v.y, 0.f),
                    fmaxf(acc[i][6] + b1v.z, 0.f), fmaxf(acc[i][7] + b1v.w, 0.f));
            }
        }
    }
}

// ---- k_gath: hrel[n] = relu(sum_{e in CSC(n)} zrel[src(e)] + relb1) ----
// wave per node, no LDS (max occupancy), 8 loads always in flight.
__global__ __launch_bounds__(256) void k_gath(const float4* __restrict__ z4,
                        const unsigned short* __restrict__ srcrow,
                        const int* __restrict__ offC,
                        const float4* __restrict__ relb1_4,
                        float4* __restrict__ hrel4) {
    int n = blockIdx.x * 4 + (threadIdx.x >> 6);
    if (n >= N) return;
    int lane = threadIdx.x & 63;
    int grp = lane >> 4;   // edge subgroup 0..3
    int q   = lane & 15;   // float4 chunk of the 64-ch row
    int b = offC[n], e_end = offC[n + 1];
    float4 acc = make_float4(0.f, 0.f, 0.f, 0.f);
    for (int i0 = b; i0 < e_end; i0 += 32) {
        int lim = e_end - i0;
        int rv = srcrow[min(i0 + lane, e_end - 1)];
        float4 v[8];
        #pragma unroll
        for (int s = 0; s < 8; ++s) {
            int src = __shfl(rv, s * 4 + grp);
            v[s] = z4[(size_t)src * 16 + q];
        }
        #pragma unroll
        for (int s = 0; s < 8; ++s) {
            if (s * 4 + grp < lim) {
                acc.x += v[s].x; acc.y += v[s].y; acc.z += v[s].z; acc.w += v[s].w;
            }
        }
    }
    #pragma unroll
    for (int m = 16; m <= 32; m <<= 1) {
        acc.x += __shfl_xor(acc.x, m);
        acc.y += __shfl_xor(acc.y, m);
        acc.z += __shfl_xor(acc.z, m);
        acc.w += __shfl_xor(acc.w, m);
    }
    if (lane < 16) {
        float4 b1 = relb1_4[q];
        float4 h;
        h.x = fmaxf(acc.x + b1.x, 0.f);
        h.y = fmaxf(acc.y + b1.y, 0.f);
        h.z = fmaxf(acc.z + b1.z, 0.f);
        h.w = fmaxf(acc.w + b1.w, 0.f);
        hrel4[(size_t)n * 16 + q] = h;
    }
}

// ---- k_mlp2g: xout = relu([hrel||hroot](Nx128) @ [Wr;Wo](128x64) + br+bo) ----
// 32-node block, 256 threads, thread tile 2 rows x 4 cols, LDS ~49 KB.
__global__ __launch_bounds__(256) void k_mlp2g(const float* __restrict__ hrel,
                        const float* __restrict__ hroot,
                        const float* __restrict__ Wr, const float* __restrict__ Wo,
                        const float* __restrict__ br, const float* __restrict__ bo,
                        float* __restrict__ xout) {
    __shared__ float As[32][132];    // [node][k]: k<64 hrel, k>=64 hroot (pad)
    __shared__ float Ws[128][64];    // [k][j]: k<64 Wr, k>=64 Wo
    int n0 = blockIdx.x * 32;
    int t = threadIdx.x;
    {
        int c4 = (t & 15) * 4;
        int r0 = t >> 4;
        #pragma unroll
        for (int r = r0; r < 32; r += 16) {
            int n = min(n0 + r, N - 1);
            *(float4*)&As[r][c4]      = *(const float4*)&hrel [(size_t)n * H + c4];
            *(float4*)&As[r][64 + c4] = *(const float4*)&hroot[(size_t)n * H + c4];
        }
    }
    for (int i = t; i < 128 * 64; i += 256) {
        int k = i >> 6, j = i & 63;
        Ws[k][j] = (k < 64) ? Wr[k * 64 + j] : Wo[(k - 64) * 64 + j];
    }
    __syncthreads();
    int tr = t >> 4;                 // rows tr*2 .. +1
    int tc = t & 15;                 // cols tc*4 .. +3
    float acc[2][4];
    #pragma unroll
    for (int i = 0; i < 2; ++i)
        #pragma unroll
        for (int j = 0; j < 4; ++j) acc[i][j] = 0.f;
    #pragma unroll 2
    for (int k = 0; k < 128; k += 4) {
        float4 a0 = *(const float4*)&As[tr * 2][k];
        float4 a1 = *(const float4*)&As[tr * 2 + 1][k];
        #pragma unroll
        for (int kk = 0; kk < 4; ++kk) {
            float4 w = *(const float4*)&Ws[k + kk][tc * 4];
            float av0 = (kk == 0) ? a0.x : (kk == 1) ? a0.y : (kk == 2) ? a0.z : a0.w;
            float av1 = (kk == 0) ? a1.x : (kk == 1) ? a1.y : (kk == 2) ? a1.z : a1.w;
            acc[0][0] += av0 * w.x; acc[0][1] += av0 * w.y;
            acc[0][2] += av0 * w.z; acc[0][3] += av0 * w.w;
            acc[1][0] += av1 * w.x; acc[1][1] += av1 * w.y;
            acc[1][2] += av1 * w.z; acc[1][3] += av1 * w.w;
        }
    }
    int jb = tc * 4;
    float4 bj;
    bj.x = br[jb]     + bo[jb];
    bj.y = br[jb + 1] + bo[jb + 1];
    bj.z = br[jb + 2] + bo[jb + 2];
    bj.w = br[jb + 3] + bo[jb + 3];
    #pragma unroll
    for (int i = 0; i < 2; ++i) {
        int n = n0 + tr * 2 + i;
        if (n < N) {
            *(float4*)&xout[(size_t)n * H + jb] = make_float4(
                fmaxf(acc[i][0] + bj.x, 0.f), fmaxf(acc[i][1] + bj.y, 0.f),
                fmaxf(acc[i][2] + bj.z, 0.f), fmaxf(acc[i][3] + bj.w, 0.f));
        }
    }
}

// ---- pooled[batch[n]] += x[n], 16-node register pre-reduce (batch sorted) ----
__global__ __launch_bounds__(256) void k_pool(const float* __restrict__ x,
                                              const int* __restrict__ batch,
                                              float* __restrict__ pooled) {
    int c = threadIdx.x & 63;
    int grp = blockIdx.x * 4 + (threadIdx.x >> 6);
    int n0 = grp * 16;
    if (n0 >= N) return;
    int nend = min(n0 + 16, N);
    int curb = batch[n0];
    float acc = 0.f;
    for (int n = n0; n < nend; ++n) {
        int b = batch[n];
        if (b != curb) {
            atomicAdd(&pooled[curb * H + c], acc);
            acc = 0.f;
            curb = b;
        }
        acc += x[(size_t)n * H + c];
    }
    atomicAdd(&pooled[curb * H + c], acc);
}

// ---- out = relu(pooled @ finW1 + finb1) @ finW2 + finb2 ----
__global__ void k_final(const float* __restrict__ pooled,
                        const float* __restrict__ W1, const float* __restrict__ b1,
                        const float* __restrict__ W2, const float* __restrict__ b2,
                        float* __restrict__ out) {
    __shared__ float h[H];
    int g = blockIdx.x;
    int j = threadIdx.x;
    const float* p = pooled + (size_t)g * H;
    float acc = b1[j];
    #pragma unroll 8
    for (int k = 0; k < H; ++k) acc += p[k] * W1[k * H + j];
    h[j] = fmaxf(acc, 0.f);
    __syncthreads();
    if (j < OUTC) {
        float o = b2[j];
        #pragma unroll 8
        for (int k = 0; k < H; ++k) o += h[k] * W2[k * OUTC + j];
        out[(size_t)g * OUTC + j] = o;
    }
}

extern "C" void kernel_launch(void* const* d_in, const int* in_sizes, int n_in,
                              void* d_out, int out_size, void* d_ws, size_t ws_size,
                              hipStream_t stream) {
    const float* x         = (const float*)d_in[0];
    const float* edge_attr = (const float*)d_in[1];
    const float* P[16];
    for (int i = 0; i < 16; ++i) P[i] = (const float*)d_in[2 + i];
    const float* finW1 = (const float*)d_in[18];
    const float* finb1 = (const float*)d_in[19];
    const float* finW2 = (const float*)d_in[20];
    const float* finb2 = (const float*)d_in[21];
    const int* row   = (const int*)d_in[22];
    const int* col   = row + E;
    const int* batch = (const int*)d_in[23];
    float* out = (float*)d_out;
    (void)ws_size; (void)n_in; (void)in_sizes; (void)out_size;

    // ---- workspace ----
    float* fw = (float*)d_ws;
    float* zrel   = fw;  fw += (size_t)N * H;   // aliased by kvR during build
    float* hroot  = fw;  fw += (size_t)N * H;
    float* x1     = fw;  fw += (size_t)N * H;   // aliased by kvC during build
    float* hrel   = fw;  fw += (size_t)N * H;
    float* ea     = fw;  fw += (size_t)N * EC;
    float* pooled = fw;  fw += (size_t)G * H;
    int* iw = (int*)fw;
    int* cntR   = iw;  iw += NB;
    int* cntC   = iw;  iw += NB;
    int* baseR  = iw;  iw += NB;
    int* baseC  = iw;  iw += NB;
    int* curR   = iw;  iw += NB;
    int* curC   = iw;  iw += NB;
    int* offR   = iw;  iw += N + 1;
    int* offC   = iw;  iw += N + 1;
    int* eid    = iw;  iw += E;
    unsigned short* srcrow = (unsigned short*)iw;  iw += E / 2;
    // 4B kv arrays alias node float arrays (build-only lifetime)
    unsigned* kvR = (unsigned*)zrel;   // E*4B = 6.4MB <= zrel's 12.8MB
    unsigned* kvC = (unsigned*)x1;

    // ---- build CSR/CSC ----
    hipMemsetAsync(cntR, 0, 2 * (size_t)NB * sizeof(int), stream);
    hipMemsetAsync(pooled, 0, (size_t)G * H * sizeof(float), stream);
    int p1grid = (E + CHUNK - 1) / CHUNK;
    k_p1hist<<<p1grid, 256, 0, stream>>>(row, col, cntR, cntC);
    k_bscan<<<1, 256, 0, stream>>>(cntR, cntC, baseR, baseC, curR, curC, offR, offC);
    k_p1scat<<<p1grid, 256, 0, stream>>>(row, col, curR, curC, kvR, kvC);
    k_p2<<<2 * NB, 256, 0, stream>>>(kvR, kvC, baseR, baseC, cntR, cntC,
                                     offR, offC, eid, srcrow);

    // ---- shared edge aggregation ----
    k_ea_gather<<<(N + 3) / 4, 256, 0, stream>>>((const float4*)edge_attr, eid, offR,
                                                 (float4*)ea);

    int gmlp = (N + 31) / 32;   // 1563

    // ---- layer 1 ----
    k_mlp1g<<<gmlp, 256, 0, stream>>>(x, ea, P[0], P[4], P[5], zrel, hroot);
    k_gath<<<(N + 3) / 4, 256, 0, stream>>>((const float4*)zrel, srcrow, offC,
                                            (const float4*)P[1], (float4*)hrel);
    k_mlp2g<<<gmlp, 256, 0, stream>>>(hrel, hroot, P[2], P[6], P[3], P[7], x1);

    // ---- layer 2 ----
    k_mlp1g<<<gmlp, 256, 0, stream>>>(x1, ea, P[8], P[12], P[13], zrel, hroot);
    k_gath<<<(N + 3) / 4, 256, 0, stream>>>((const float4*)zrel, srcrow, offC,
                                            (const float4*)P[9], (float4*)hrel);
    k_mlp2g<<<gmlp, 256, 0, stream>>>(hrel, hroot, P[10], P[14], P[11], P[15], x1);

    // ---- pool + head ----
    k_pool<<<(N / 16 + 3) / 4, 256, 0, stream>>>(x1, batch, pooled);
    k_final<<<G, 64, 0, stream>>>(pooled, finW1, finb1, finW2, finb2, out);
}

// Round 5
// 628.322 us; speedup vs baseline: 1.1455x; 1.0345x over previous
//
#include <hip/hip_runtime.h>

// NetEdge GNN round 11 (base r10 = 650us). Bundle:
//  1. Gather load-guards: degree~Poisson(32) made unconditional 32-edge chunk
//     loads issue ~1.45x the logical bytes (E[32*ceil(d/32)-d]~=14/node).
//     Guard moved BEFORE the load (group-uniform cond -> exec-masked load,
//     still 8 independent loads in flight). ~-30% gather traffic.
//  2. p1hist writes per-block histograms; p1scat skips its re-histogram
//     (-12.8MB re-read, -6.4M LDS atomics). Cursor semantics unchanged.
//  3. Pool fused into layer-2 k_mlp2g: block-segmented reduction via reused
//     As LDS, ~1 atomic/thread (NOT r9's per-node atomics). Saves x1
//     write+read (25.6MB) + k_pool launch.
//  4. Nontemporal loads for once-read streams in ea_gather (edge_attr, eid).

namespace {
constexpr int N  = 50000;    // nodes
constexpr int E  = 1600000;  // edges
constexpr int G  = 256;      // graphs
constexpr int EC = 32;       // edge channels
constexpr int H  = 64;       // hidden / node channels
constexpr int OUTC = 10;     // classes
constexpr int NB = (N + 255) / 256;   // 196 coarse buckets (node >> 8)
constexpr int CHUNK = 4096;           // edges per pass-1 block
constexpr int P1G = (E + CHUNK - 1) / CHUNK;  // 391 pass-1 blocks
}

typedef float f4v __attribute__((ext_vector_type(4)));

static __device__ inline float4 ntload4(const float4* p) {
    f4v t = __builtin_nontemporal_load((const f4v*)p);
    return make_float4(t.x, t.y, t.z, t.w);
}

// ---- pass 1a: coarse histograms + per-block histograms ----
__global__ __launch_bounds__(256) void k_p1hist(const int* __restrict__ row,
                                                const int* __restrict__ col,
                                                int* __restrict__ cntR,
                                                int* __restrict__ cntC,
                                                int* __restrict__ bhR,
                                                int* __restrict__ bhC) {
    __shared__ int hR[NB], hC[NB];
    for (int i = threadIdx.x; i < NB; i += 256) { hR[i] = 0; hC[i] = 0; }
    __syncthreads();
    int base = blockIdx.x * CHUNK;
    int end = min(base + CHUNK, E);
    for (int e = base + threadIdx.x; e < end; e += 256) {
        atomicAdd(&hR[row[e] >> 8], 1);
        atomicAdd(&hC[col[e] >> 8], 1);
    }
    __syncthreads();
    int* bR = bhR + (size_t)blockIdx.x * NB;
    int* bC = bhC + (size_t)blockIdx.x * NB;
    for (int i = threadIdx.x; i < NB; i += 256) {
        int a = hR[i], b = hC[i];
        bR[i] = a; bC[i] = b;
        if (a) atomicAdd(&cntR[i], a);
        if (b) atomicAdd(&cntC[i], b);
    }
}

// ---- pass 1b: scan bucket counts -> bases + cursors; off[N]=E ----
__global__ __launch_bounds__(256) void k_bscan(const int* __restrict__ cntR,
                                               const int* __restrict__ cntC,
                                               int* __restrict__ baseR, int* __restrict__ baseC,
                                               int* __restrict__ curR,  int* __restrict__ curC,
                                               int* __restrict__ offR,  int* __restrict__ offC) {
    __shared__ int sR[256], sC[256];
    int t = threadIdx.x;
    sR[t] = (t < NB) ? cntR[t] : 0;
    sC[t] = (t < NB) ? cntC[t] : 0;
    __syncthreads();
    for (int d = 1; d < 256; d <<= 1) {
        int vR = sR[t], vC = sC[t];
        int uR = (t >= d) ? sR[t - d] : 0;
        int uC = (t >= d) ? sC[t - d] : 0;
        __syncthreads();
        sR[t] = vR + uR; sC[t] = vC + uC;
        __syncthreads();
    }
    if (t < NB) {
        int bR = (t == 0) ? 0 : sR[t - 1];
        int bC = (t == 0) ? 0 : sC[t - 1];
        baseR[t] = bR; curR[t] = bR;
        baseC[t] = bC; curC[t] = bC;
    }
    if (t == 0) { offR[N] = E; offC[N] = E; }
}

// ---- pass 1c: coarse scatter of packed ((key&255)<<24 | val), 4B ----
// Per-block hist comes precomputed from k_p1hist (no re-histogram pass).
__global__ __launch_bounds__(256) void k_p1scat(const int* __restrict__ row,
                                                const int* __restrict__ col,
                                                const int* __restrict__ bhR,
                                                const int* __restrict__ bhC,
                                                int* __restrict__ curR, int* __restrict__ curC,
                                                unsigned* __restrict__ kvR,
                                                unsigned* __restrict__ kvC) {
    __shared__ int cR[NB], cC[NB];
    const int* bR = bhR + (size_t)blockIdx.x * NB;
    const int* bC = bhC + (size_t)blockIdx.x * NB;
    for (int i = threadIdx.x; i < NB; i += 256) {
        int a = bR[i], b = bC[i];
        cR[i] = a ? atomicAdd(&curR[i], a) : 0;
        cC[i] = b ? atomicAdd(&curC[i], b) : 0;
    }
    __syncthreads();
    int base = blockIdx.x * CHUNK;
    int end = min(base + CHUNK, E);
    for (int e = base + threadIdx.x; e < end; e += 256) {
        int r = row[e], c = col[e];
        int pR = atomicAdd(&cR[r >> 8], 1);
        kvR[pR] = ((unsigned)(r & 255) << 24) | (unsigned)e;   // e < 2^24
        int pC = atomicAdd(&cC[c >> 8], 1);
        kvC[pC] = ((unsigned)(c & 255) << 24) | (unsigned)r;   // r < 2^24
    }
}

// ---- pass 2: per-bucket fine bin (4B kv; C-side emits ushort srcrow) ----
__global__ __launch_bounds__(256) void k_p2(const unsigned* __restrict__ kvR,
                                            const unsigned* __restrict__ kvC,
                                            const int* __restrict__ baseR, const int* __restrict__ baseC,
                                            const int* __restrict__ cntR,  const int* __restrict__ cntC,
                                            int* __restrict__ offR, int* __restrict__ offC,
                                            int* __restrict__ eid,
                                            unsigned short* __restrict__ srcrow) {
    bool isC = blockIdx.x >= NB;
    int b = isC ? blockIdx.x - NB : blockIdx.x;
    const unsigned* kv = isC ? kvC : kvR;
    int sbase = isC ? baseC[b] : baseR[b];
    int scnt  = isC ? cntC[b]  : cntR[b];
    int* off  = isC ? offC : offR;

    __shared__ int hist[256], s[256], cur[256];
    int t = threadIdx.x;
    hist[t] = 0;
    __syncthreads();
    for (int i = sbase + t; i < sbase + scnt; i += 256) {
        atomicAdd(&hist[kv[i] >> 24], 1);
    }
    __syncthreads();
    s[t] = hist[t];
    __syncthreads();
    for (int d = 1; d < 256; d <<= 1) {
        int v = s[t];
        int u = (t >= d) ? s[t - d] : 0;
        __syncthreads();
        s[t] = v + u;
        __syncthreads();
    }
    int excl = (t == 0) ? 0 : s[t - 1];
    cur[t] = sbase + excl;
    int node = (b << 8) + t;
    if (node < N) off[node] = sbase + excl;
    __syncthreads();
    for (int i = sbase + t; i < sbase + scnt; i += 256) {
        unsigned p = kv[i];
        int lk = p >> 24;
        int pos = atomicAdd(&cur[lk], 1);
        int val = (int)(p & 0xFFFFFFu);
        if (isC) srcrow[pos] = (unsigned short)val;
        else     eid[pos] = val;
    }
}

// ---- ea[n] = sum of edge_attr over outgoing edges; float4, 8 edges/load ----
// Tail chunks guard the LOAD (group-uniform cond), not just the accumulate.
__global__ __launch_bounds__(256) void k_ea_gather(const float4* __restrict__ ea4_in,
                                                   const int* __restrict__ eid,
                                                   const int* __restrict__ offR,
                                                   float4* __restrict__ ea_out) {
    int n = blockIdx.x * 4 + (threadIdx.x >> 6);
    int lane = threadIdx.x & 63;
    if (n >= N) return;
    int grp = lane >> 3;
    int q   = lane & 7;
    int b = offR[n], e_end = offR[n + 1];
    float4 acc = make_float4(0.f, 0.f, 0.f, 0.f);
    for (int i0 = b; i0 < e_end; i0 += 32) {
        int lim = e_end - i0;
        int ev = __builtin_nontemporal_load(&eid[min(i0 + lane, e_end - 1)]);
        int e[4];
        #pragma unroll
        for (int s = 0; s < 4; ++s) e[s] = __shfl(ev, s * 8 + grp);
        if (lim >= 32) {
            float4 v[4];
            #pragma unroll
            for (int s = 0; s < 4; ++s) v[s] = ntload4(&ea4_in[(size_t)e[s] * 8 + q]);
            #pragma unroll
            for (int s = 0; s < 4; ++s) {
                acc.x += v[s].x; acc.y += v[s].y; acc.z += v[s].z; acc.w += v[s].w;
            }
        } else {
            float4 v[4];
            #pragma unroll
            for (int s = 0; s < 4; ++s) {
                if (s * 8 + grp < lim) v[s] = ntload4(&ea4_in[(size_t)e[s] * 8 + q]);
            }
            #pragma unroll
            for (int s = 0; s < 4; ++s) {
                if (s * 8 + grp < lim) {
                    acc.x += v[s].x; acc.y += v[s].y; acc.z += v[s].z; acc.w += v[s].w;
                }
            }
        }
    }
    #pragma unroll
    for (int m = 8; m <= 32; m <<= 1) {
        acc.x += __shfl_xor(acc.x, m);
        acc.y += __shfl_xor(acc.y, m);
        acc.z += __shfl_xor(acc.z, m);
        acc.w += __shfl_xor(acc.w, m);
    }
    if (lane < 8) ea_out[(size_t)n * 8 + q] = acc;
}

// ---- k_mlp1g: C[n,0:64]=zrel=[x||ea]@Wz, C[n,64:128]=relu([x||ea]@Wh+bh) ----
__global__ __launch_bounds__(256) void k_mlp1g(const float* __restrict__ x,
                        const float* __restrict__ ea,
                        const float* __restrict__ Wz, const float* __restrict__ Wh,
                        const float* __restrict__ bh,
                        float* __restrict__ zrel, float* __restrict__ hroot) {
    __shared__ float As[32][100];    // [node][k], 96 padded to 100
    __shared__ float Ws[96][128];    // [k][j]: j<64 -> Wz, j>=64 -> Wh
    int n0 = blockIdx.x * 32;
    int t = threadIdx.x;
    {   // stage x (cols 0..63)
        int c4 = (t & 15) * 4;
        int r0 = t >> 4;
        #pragma unroll
        for (int r = r0; r < 32; r += 16) {
            int n = min(n0 + r, N - 1);
            *(float4*)&As[r][c4] = *(const float4*)&x[(size_t)n * H + c4];
        }
        // stage ea (cols 64..95)
        int c2 = (t & 7) * 4;
        int r1 = t >> 3;             // 0..31
        int n = min(n0 + r1, N - 1);
        *(float4*)&As[r1][64 + c2] = *(const float4*)&ea[(size_t)n * EC + c2];
    }
    for (int i = t; i < 96 * 128; i += 256) {
        int k = i >> 7, j = i & 127;
        Ws[k][j] = (j < 64) ? Wz[k * 64 + j] : Wh[k * 64 + (j - 64)];
    }
    __syncthreads();
    int tr = t >> 4;                 // rows tr*2 .. tr*2+1
    int tc = t & 15;                 // cols tc*8 .. tc*8+7
    float acc[2][8];
    #pragma unroll
    for (int i = 0; i < 2; ++i)
        #pragma unroll
        for (int j = 0; j < 8; ++j) acc[i][j] = 0.f;
    #pragma unroll 2
    for (int k = 0; k < 96; k += 4) {
        float4 a0 = *(const float4*)&As[tr * 2][k];
        float4 a1 = *(const float4*)&As[tr * 2 + 1][k];
        #pragma unroll
        for (int kk = 0; kk < 4; ++kk) {
            float4 w0 = *(const float4*)&Ws[k + kk][tc * 8];
            float4 w1 = *(const float4*)&Ws[k + kk][tc * 8 + 4];
            float av0 = (kk == 0) ? a0.x : (kk == 1) ? a0.y : (kk == 2) ? a0.z : a0.w;
            float av1 = (kk == 0) ? a1.x : (kk == 1) ? a1.y : (kk == 2) ? a1.z : a1.w;
            acc[0][0] += av0 * w0.x; acc[0][1] += av0 * w0.y;
            acc[0][2] += av0 * w0.z; acc[0][3] += av0 * w0.w;
            acc[0][4] += av0 * w1.x; acc[0][5] += av0 * w1.y;
            acc[0][6] += av0 * w1.z; acc[0][7] += av0 * w1.w;
            acc[1][0] += av1 * w0.x; acc[1][1] += av1 * w0.y;
            acc[1][2] += av1 * w0.z; acc[1][3] += av1 * w0.w;
            acc[1][4] += av1 * w1.x; acc[1][5] += av1 * w1.y;
            acc[1][6] += av1 * w1.z; acc[1][7] += av1 * w1.w;
        }
    }
    if (tc < 8) {                    // zrel cols, no bias, no relu
        int jb = tc * 8;
        #pragma unroll
        for (int i = 0; i < 2; ++i) {
            int n = n0 + tr * 2 + i;
            if (n < N) {
                *(float4*)&zrel[(size_t)n * H + jb] =
                    make_float4(acc[i][0], acc[i][1], acc[i][2], acc[i][3]);
                *(float4*)&zrel[(size_t)n * H + jb + 4] =
                    make_float4(acc[i][4], acc[i][5], acc[i][6], acc[i][7]);
            }
        }
    } else {                         // hroot cols, +bias, relu
        int jb = (tc - 8) * 8;
        float4 b0 = *(const float4*)&bh[jb];
        float4 b1v = *(const float4*)&bh[jb + 4];
        #pragma unroll
        for (int i = 0; i < 2; ++i) {
            int n = n0 + tr * 2 + i;
            if (n < N) {
                *(float4*)&hroot[(size_t)n * H + jb] = make_float4(
                    fmaxf(acc[i][0] + b0.x, 0.f), fmaxf(acc[i][1] + b0.y, 0.f),
                    fmaxf(acc[i][2] + b0.z, 0.f), fmaxf(acc[i][3] + b0.w, 0.f));
                *(float4*)&hroot[(size_t)n * H + jb + 4] = make_float4(
                    fmaxf(acc[i][4] + b1v.x, 0.f), fmaxf(acc[i][5] + b1v.y, 0.f),
                    fmaxf(acc[i][6] + b1v.z, 0.f), fmaxf(acc[i][7] + b1v.w, 0.f));
            }
        }
    }
}

// ---- k_gath: hrel[n] = relu(sum_{e in CSC(n)} zrel[src(e)] + relb1) ----
// wave per node, no LDS; tail chunks guard the LOAD, not just the accumulate.
__global__ __launch_bounds__(256) void k_gath(const float4* __restrict__ z4,
                        const unsigned short* __restrict__ srcrow,
                        const int* __restrict__ offC,
                        const float4* __restrict__ relb1_4,
                        float4* __restrict__ hrel4) {
    int n = blockIdx.x * 4 + (threadIdx.x >> 6);
    if (n >= N) return;
    int lane = threadIdx.x & 63;
    int grp = lane >> 4;   // edge subgroup 0..3
    int q   = lane & 15;   // float4 chunk of the 64-ch row
    int b = offC[n], e_end = offC[n + 1];
    float4 acc = make_float4(0.f, 0.f, 0.f, 0.f);
    for (int i0 = b; i0 < e_end; i0 += 32) {
        int lim = e_end - i0;
        int rv = srcrow[min(i0 + lane, e_end - 1)];
        int src[8];
        #pragma unroll
        for (int s = 0; s < 8; ++s) src[s] = __shfl(rv, s * 4 + grp);
        if (lim >= 32) {
            float4 v[8];
            #pragma unroll
            for (int s = 0; s < 8; ++s) v[s] = z4[(size_t)src[s] * 16 + q];
            #pragma unroll
            for (int s = 0; s < 8; ++s) {
                acc.x += v[s].x; acc.y += v[s].y; acc.z += v[s].z; acc.w += v[s].w;
            }
        } else {
            float4 v[8];
            #pragma unroll
            for (int s = 0; s < 8; ++s) {
                if (s * 4 + grp < lim) v[s] = z4[(size_t)src[s] * 16 + q];
            }
            #pragma unroll
            for (int s = 0; s < 8; ++s) {
                if (s * 4 + grp < lim) {
                    acc.x += v[s].x; acc.y += v[s].y; acc.z += v[s].z; acc.w += v[s].w;
                }
            }
        }
    }
    #pragma unroll
    for (int m = 16; m <= 32; m <<= 1) {
        acc.x += __shfl_xor(acc.x, m);
        acc.y += __shfl_xor(acc.y, m);
        acc.z += __shfl_xor(acc.z, m);
        acc.w += __shfl_xor(acc.w, m);
    }
    if (lane < 16) {
        float4 b1 = relb1_4[q];
        float4 h;
        h.x = fmaxf(acc.x + b1.x, 0.f);
        h.y = fmaxf(acc.y + b1.y, 0.f);
        h.z = fmaxf(acc.z + b1.z, 0.f);
        h.w = fmaxf(acc.w + b1.w, 0.f);
        hrel4[(size_t)n * 16 + q] = h;
    }
}

// ---- k_mlp2g: xout = relu([hrel||hroot](Nx128) @ [Wr;Wo](128x64) + br+bo)
//      dopool: block-segmented pool via reused As LDS (~1 atomic/thread) ----
__global__ __launch_bounds__(256) void k_mlp2g(const float* __restrict__ hrel,
                        const float* __restrict__ hroot,
                        const float* __restrict__ Wr, const float* __restrict__ Wo,
                        const float* __restrict__ br, const float* __restrict__ bo,
                        float* __restrict__ xout,
                        const int* __restrict__ batch, float* __restrict__ pooled,
                        int dopool) {
    __shared__ float As[32][132];    // [node][k]: k<64 hrel, k>=64 hroot (pad)
    __shared__ float Ws[128][64];    // [k][j]: k<64 Wr, k>=64 Wo
    __shared__ int sB[32];
    int n0 = blockIdx.x * 32;
    int t = threadIdx.x;
    {
        int c4 = (t & 15) * 4;
        int r0 = t >> 4;
        #pragma unroll
        for (int r = r0; r < 32; r += 16) {
            int n = min(n0 + r, N - 1);
            *(float4*)&As[r][c4]      = *(const float4*)&hrel [(size_t)n * H + c4];
            *(float4*)&As[r][64 + c4] = *(const float4*)&hroot[(size_t)n * H + c4];
        }
    }
    if (dopool && t < 32) sB[t] = batch[min(n0 + t, N - 1)];
    for (int i = t; i < 128 * 64; i += 256) {
        int k = i >> 6, j = i & 63;
        Ws[k][j] = (k < 64) ? Wr[k * 64 + j] : Wo[(k - 64) * 64 + j];
    }
    __syncthreads();
    int tr = t >> 4;                 // rows tr*2 .. +1
    int tc = t & 15;                 // cols tc*4 .. +3
    float acc[2][4];
    #pragma unroll
    for (int i = 0; i < 2; ++i)
        #pragma unroll
        for (int j = 0; j < 4; ++j) acc[i][j] = 0.f;
    #pragma unroll 2
    for (int k = 0; k < 128; k += 4) {
        float4 a0 = *(const float4*)&As[tr * 2][k];
        float4 a1 = *(const float4*)&As[tr * 2 + 1][k];
        #pragma unroll
        for (int kk = 0; kk < 4; ++kk) {
            float4 w = *(const float4*)&Ws[k + kk][tc * 4];
            float av0 = (kk == 0) ? a0.x : (kk == 1) ? a0.y : (kk == 2) ? a0.z : a0.w;
            float av1 = (kk == 0) ? a1.x : (kk == 1) ? a1.y : (kk == 2) ? a1.z : a1.w;
            acc[0][0] += av0 * w.x; acc[0][1] += av0 * w.y;
            acc[0][2] += av0 * w.z; acc[0][3] += av0 * w.w;
            acc[1][0] += av1 * w.x; acc[1][1] += av1 * w.y;
            acc[1][2] += av1 * w.z; acc[1][3] += av1 * w.w;
        }
    }
    int jb = tc * 4;
    float4 bj;
    bj.x = br[jb]     + bo[jb];
    bj.y = br[jb + 1] + bo[jb + 1];
    bj.z = br[jb + 2] + bo[jb + 2];
    bj.w = br[jb + 3] + bo[jb + 3];
    if (!dopool) {
        #pragma unroll
        for (int i = 0; i < 2; ++i) {
            int n = n0 + tr * 2 + i;
            if (n < N) {
                *(float4*)&xout[(size_t)n * H + jb] = make_float4(
                    fmaxf(acc[i][0] + bj.x, 0.f), fmaxf(acc[i][1] + bj.y, 0.f),
                    fmaxf(acc[i][2] + bj.z, 0.f), fmaxf(acc[i][3] + bj.w, 0.f));
            }
        }
    } else {
        __syncthreads();             // all GEMM reads of As done
        #pragma unroll
        for (int i = 0; i < 2; ++i) {
            int r = tr * 2 + i;
            As[r][jb + 0] = fmaxf(acc[i][0] + bj.x, 0.f);
            As[r][jb + 1] = fmaxf(acc[i][1] + bj.y, 0.f);
            As[r][jb + 2] = fmaxf(acc[i][2] + bj.z, 0.f);
            As[r][jb + 3] = fmaxf(acc[i][3] + bj.w, 0.f);
        }
        __syncthreads();
        // thread t: channel t&63, row group t>>6 (8 rows), segmented by batch
        int ch = t & 63, rg = t >> 6;
        int r0 = rg * 8;
        if (n0 + r0 < N) {
            float a = 0.f;
            int curb = sB[r0];
            for (int r = r0; r < r0 + 8; ++r) {
                int n = n0 + r;
                if (n >= N) break;
                int bb = sB[r];
                if (bb != curb) {
                    atomicAdd(&pooled[(size_t)curb * H + ch], a);
                    a = 0.f; curb = bb;
                }
                a += As[r][ch];
            }
            atomicAdd(&pooled[(size_t)curb * H + ch], a);
        }
    }
}

// ---- out = relu(pooled @ finW1 + finb1) @ finW2 + finb2 ----
__global__ void k_final(const float* __restrict__ pooled,
                        const float* __restrict__ W1, const float* __restrict__ b1,
                        const float* __restrict__ W2, const float* __restrict__ b2,
                        float* __restrict__ out) {
    __shared__ float h[H];
    int g = blockIdx.x;
    int j = threadIdx.x;
    const float* p = pooled + (size_t)g * H;
    float acc = b1[j];
    #pragma unroll 8
    for (int k = 0; k < H; ++k) acc += p[k] * W1[k * H + j];
    h[j] = fmaxf(acc, 0.f);
    __syncthreads();
    if (j < OUTC) {
        float o = b2[j];
        #pragma unroll 8
        for (int k = 0; k < H; ++k) o += h[k] * W2[k * OUTC + j];
        out[(size_t)g * OUTC + j] = o;
    }
}

extern "C" void kernel_launch(void* const* d_in, const int* in_sizes, int n_in,
                              void* d_out, int out_size, void* d_ws, size_t ws_size,
                              hipStream_t stream) {
    const float* x         = (const float*)d_in[0];
    const float* edge_attr = (const float*)d_in[1];
    const float* P[16];
    for (int i = 0; i < 16; ++i) P[i] = (const float*)d_in[2 + i];
    const float* finW1 = (const float*)d_in[18];
    const float* finb1 = (const float*)d_in[19];
    const float* finW2 = (const float*)d_in[20];
    const float* finb2 = (const float*)d_in[21];
    const int* row   = (const int*)d_in[22];
    const int* col   = row + E;
    const int* batch = (const int*)d_in[23];
    float* out = (float*)d_out;
    (void)ws_size; (void)n_in; (void)in_sizes; (void)out_size;

    // ---- workspace ----
    float* fw = (float*)d_ws;
    float* zrel   = fw;  fw += (size_t)N * H;   // aliased by kvR during build
    float* hroot  = fw;  fw += (size_t)N * H;
    float* x1     = fw;  fw += (size_t)N * H;   // aliased by kvC during build
    float* hrel   = fw;  fw += (size_t)N * H;
    float* ea     = fw;  fw += (size_t)N * EC;
    float* pooled = fw;  fw += (size_t)G * H;
    int* iw = (int*)fw;
    int* cntR   = iw;  iw += NB;
    int* cntC   = iw;  iw += NB;
    int* baseR  = iw;  iw += NB;
    int* baseC  = iw;  iw += NB;
    int* curR   = iw;  iw += NB;
    int* curC   = iw;  iw += NB;
    int* offR   = iw;  iw += N + 1;
    int* offC   = iw;  iw += N + 1;
    int* eid    = iw;  iw += E;
    unsigned short* srcrow = (unsigned short*)iw;  iw += E / 2;
    int* bhR    = iw;  iw += P1G * NB;
    int* bhC    = iw;  iw += P1G * NB;
    // 4B kv arrays alias node float arrays (build-only lifetime)
    unsigned* kvR = (unsigned*)zrel;   // E*4B = 6.4MB <= zrel's 12.8MB
    unsigned* kvC = (unsigned*)x1;

    // ---- build CSR/CSC ----
    hipMemsetAsync(cntR, 0, 2 * (size_t)NB * sizeof(int), stream);
    hipMemsetAsync(pooled, 0, (size_t)G * H * sizeof(float), stream);
    k_p1hist<<<P1G, 256, 0, stream>>>(row, col, cntR, cntC, bhR, bhC);
    k_bscan<<<1, 256, 0, stream>>>(cntR, cntC, baseR, baseC, curR, curC, offR, offC);
    k_p1scat<<<P1G, 256, 0, stream>>>(row, col, bhR, bhC, curR, curC, kvR, kvC);
    k_p2<<<2 * NB, 256, 0, stream>>>(kvR, kvC, baseR, baseC, cntR, cntC,
                                     offR, offC, eid, srcrow);

    // ---- shared edge aggregation ----
    k_ea_gather<<<(N + 3) / 4, 256, 0, stream>>>((const float4*)edge_attr, eid, offR,
                                                 (float4*)ea);

    int gmlp = (N + 31) / 32;   // 1563

    // ---- layer 1 ----
    k_mlp1g<<<gmlp, 256, 0, stream>>>(x, ea, P[0], P[4], P[5], zrel, hroot);
    k_gath<<<(N + 3) / 4, 256, 0, stream>>>((const float4*)zrel, srcrow, offC,
                                            (const float4*)P[1], (float4*)hrel);
    k_mlp2g<<<gmlp, 256, 0, stream>>>(hrel, hroot, P[2], P[6], P[3], P[7], x1,
                                      batch, pooled, 0);

    // ---- layer 2 (mlp2 + pool fused, block-segmented) ----
    k_mlp1g<<<gmlp, 256, 0, stream>>>(x1, ea, P[8], P[12], P[13], zrel, hroot);
    k_gath<<<(N + 3) / 4, 256, 0, stream>>>((const float4*)zrel, srcrow, offC,
                                            (const float4*)P[9], (float4*)hrel);
    k_mlp2g<<<gmlp, 256, 0, stream>>>(hrel, hroot, P[10], P[14], P[11], P[15], x1,
                                      batch, pooled, 1);

    // ---- head ----
    k_final<<<G, 64, 0, stream>>>(pooled, finW1, finb1, finW2, finb2, out);
}

// Round 6
// 593.228 us; speedup vs baseline: 1.2133x; 1.0592x over previous
//
#include <hip/hip_runtime.h>
#include <hip/hip_fp16.h>

// NetEdge GNN round 12 (base r11 = 628us). Single change: fp16 zrel.
// k_gath's operand (zrel) stored as __half: gather bytes halve (410->205 MB
// logical per layer) AND working set halves (12.8->6.4 MB -> much larger
// per-XCD L2-resident fraction). Accumulation stays fp32; only storage is
// quantized (pre-activation values |z|<~5, fp16 rel err 2^-11 -> predicted
// output absmax ~5e-3..1e-2; checker passed 3.9e-3 last round).
// k_gath restructure for 128B rows: grp=lane>>3 (8 edges/round), q=lane&7
// (16B uint4 chunk), 4 loads in flight per 32-edge chunk, guarded tail.
// Everything else identical to r11.

namespace {
constexpr int N  = 50000;    // nodes
constexpr int E  = 1600000;  // edges
constexpr int G  = 256;      // graphs
constexpr int EC = 32;       // edge channels
constexpr int H  = 64;       // hidden / node channels
constexpr int OUTC = 10;     // classes
constexpr int NB = (N + 255) / 256;   // 196 coarse buckets (node >> 8)
constexpr int CHUNK = 4096;           // edges per pass-1 block
constexpr int P1G = (E + CHUNK - 1) / CHUNK;  // 391 pass-1 blocks
}

typedef float f4v __attribute__((ext_vector_type(4)));

static __device__ inline float4 ntload4(const float4* p) {
    f4v t = __builtin_nontemporal_load((const f4v*)p);
    return make_float4(t.x, t.y, t.z, t.w);
}

// ---- pass 1a: coarse histograms + per-block histograms ----
__global__ __launch_bounds__(256) void k_p1hist(const int* __restrict__ row,
                                                const int* __restrict__ col,
                                                int* __restrict__ cntR,
                                                int* __restrict__ cntC,
                                                int* __restrict__ bhR,
                                                int* __restrict__ bhC) {
    __shared__ int hR[NB], hC[NB];
    for (int i = threadIdx.x; i < NB; i += 256) { hR[i] = 0; hC[i] = 0; }
    __syncthreads();
    int base = blockIdx.x * CHUNK;
    int end = min(base + CHUNK, E);
    for (int e = base + threadIdx.x; e < end; e += 256) {
        atomicAdd(&hR[row[e] >> 8], 1);
        atomicAdd(&hC[col[e] >> 8], 1);
    }
    __syncthreads();
    int* bR = bhR + (size_t)blockIdx.x * NB;
    int* bC = bhC + (size_t)blockIdx.x * NB;
    for (int i = threadIdx.x; i < NB; i += 256) {
        int a = hR[i], b = hC[i];
        bR[i] = a; bC[i] = b;
        if (a) atomicAdd(&cntR[i], a);
        if (b) atomicAdd(&cntC[i], b);
    }
}

// ---- pass 1b: scan bucket counts -> bases + cursors; off[N]=E ----
__global__ __launch_bounds__(256) void k_bscan(const int* __restrict__ cntR,
                                               const int* __restrict__ cntC,
                                               int* __restrict__ baseR, int* __restrict__ baseC,
                                               int* __restrict__ curR,  int* __restrict__ curC,
                                               int* __restrict__ offR,  int* __restrict__ offC) {
    __shared__ int sR[256], sC[256];
    int t = threadIdx.x;
    sR[t] = (t < NB) ? cntR[t] : 0;
    sC[t] = (t < NB) ? cntC[t] : 0;
    __syncthreads();
    for (int d = 1; d < 256; d <<= 1) {
        int vR = sR[t], vC = sC[t];
        int uR = (t >= d) ? sR[t - d] : 0;
        int uC = (t >= d) ? sC[t - d] : 0;
        __syncthreads();
        sR[t] = vR + uR; sC[t] = vC + uC;
        __syncthreads();
    }
    if (t < NB) {
        int bR = (t == 0) ? 0 : sR[t - 1];
        int bC = (t == 0) ? 0 : sC[t - 1];
        baseR[t] = bR; curR[t] = bR;
        baseC[t] = bC; curC[t] = bC;
    }
    if (t == 0) { offR[N] = E; offC[N] = E; }
}

// ---- pass 1c: coarse scatter of packed ((key&255)<<24 | val), 4B ----
__global__ __launch_bounds__(256) void k_p1scat(const int* __restrict__ row,
                                                const int* __restrict__ col,
                                                const int* __restrict__ bhR,
                                                const int* __restrict__ bhC,
                                                int* __restrict__ curR, int* __restrict__ curC,
                                                unsigned* __restrict__ kvR,
                                                unsigned* __restrict__ kvC) {
    __shared__ int cR[NB], cC[NB];
    const int* bR = bhR + (size_t)blockIdx.x * NB;
    const int* bC = bhC + (size_t)blockIdx.x * NB;
    for (int i = threadIdx.x; i < NB; i += 256) {
        int a = bR[i], b = bC[i];
        cR[i] = a ? atomicAdd(&curR[i], a) : 0;
        cC[i] = b ? atomicAdd(&curC[i], b) : 0;
    }
    __syncthreads();
    int base = blockIdx.x * CHUNK;
    int end = min(base + CHUNK, E);
    for (int e = base + threadIdx.x; e < end; e += 256) {
        int r = row[e], c = col[e];
        int pR = atomicAdd(&cR[r >> 8], 1);
        kvR[pR] = ((unsigned)(r & 255) << 24) | (unsigned)e;   // e < 2^24
        int pC = atomicAdd(&cC[c >> 8], 1);
        kvC[pC] = ((unsigned)(c & 255) << 24) | (unsigned)r;   // r < 2^24
    }
}

// ---- pass 2: per-bucket fine bin (4B kv; C-side emits ushort srcrow) ----
__global__ __launch_bounds__(256) void k_p2(const unsigned* __restrict__ kvR,
                                            const unsigned* __restrict__ kvC,
                                            const int* __restrict__ baseR, const int* __restrict__ baseC,
                                            const int* __restrict__ cntR,  const int* __restrict__ cntC,
                                            int* __restrict__ offR, int* __restrict__ offC,
                                            int* __restrict__ eid,
                                            unsigned short* __restrict__ srcrow) {
    bool isC = blockIdx.x >= NB;
    int b = isC ? blockIdx.x - NB : blockIdx.x;
    const unsigned* kv = isC ? kvC : kvR;
    int sbase = isC ? baseC[b] : baseR[b];
    int scnt  = isC ? cntC[b]  : cntR[b];
    int* off  = isC ? offC : offR;

    __shared__ int hist[256], s[256], cur[256];
    int t = threadIdx.x;
    hist[t] = 0;
    __syncthreads();
    for (int i = sbase + t; i < sbase + scnt; i += 256) {
        atomicAdd(&hist[kv[i] >> 24], 1);
    }
    __syncthreads();
    s[t] = hist[t];
    __syncthreads();
    for (int d = 1; d < 256; d <<= 1) {
        int v = s[t];
        int u = (t >= d) ? s[t - d] : 0;
        __syncthreads();
        s[t] = v + u;
        __syncthreads();
    }
    int excl = (t == 0) ? 0 : s[t - 1];
    cur[t] = sbase + excl;
    int node = (b << 8) + t;
    if (node < N) off[node] = sbase + excl;
    __syncthreads();
    for (int i = sbase + t; i < sbase + scnt; i += 256) {
        unsigned p = kv[i];
        int lk = p >> 24;
        int pos = atomicAdd(&cur[lk], 1);
        int val = (int)(p & 0xFFFFFFu);
        if (isC) srcrow[pos] = (unsigned short)val;
        else     eid[pos] = val;
    }
}

// ---- ea[n] = sum of edge_attr over outgoing edges; float4, 8 edges/load ----
__global__ __launch_bounds__(256) void k_ea_gather(const float4* __restrict__ ea4_in,
                                                   const int* __restrict__ eid,
                                                   const int* __restrict__ offR,
                                                   float4* __restrict__ ea_out) {
    int n = blockIdx.x * 4 + (threadIdx.x >> 6);
    int lane = threadIdx.x & 63;
    if (n >= N) return;
    int grp = lane >> 3;
    int q   = lane & 7;
    int b = offR[n], e_end = offR[n + 1];
    float4 acc = make_float4(0.f, 0.f, 0.f, 0.f);
    for (int i0 = b; i0 < e_end; i0 += 32) {
        int lim = e_end - i0;
        int ev = __builtin_nontemporal_load(&eid[min(i0 + lane, e_end - 1)]);
        int e[4];
        #pragma unroll
        for (int s = 0; s < 4; ++s) e[s] = __shfl(ev, s * 8 + grp);
        if (lim >= 32) {
            float4 v[4];
            #pragma unroll
            for (int s = 0; s < 4; ++s) v[s] = ntload4(&ea4_in[(size_t)e[s] * 8 + q]);
            #pragma unroll
            for (int s = 0; s < 4; ++s) {
                acc.x += v[s].x; acc.y += v[s].y; acc.z += v[s].z; acc.w += v[s].w;
            }
        } else {
            float4 v[4];
            #pragma unroll
            for (int s = 0; s < 4; ++s) {
                if (s * 8 + grp < lim) v[s] = ntload4(&ea4_in[(size_t)e[s] * 8 + q]);
            }
            #pragma unroll
            for (int s = 0; s < 4; ++s) {
                if (s * 8 + grp < lim) {
                    acc.x += v[s].x; acc.y += v[s].y; acc.z += v[s].z; acc.w += v[s].w;
                }
            }
        }
    }
    #pragma unroll
    for (int m = 8; m <= 32; m <<= 1) {
        acc.x += __shfl_xor(acc.x, m);
        acc.y += __shfl_xor(acc.y, m);
        acc.z += __shfl_xor(acc.z, m);
        acc.w += __shfl_xor(acc.w, m);
    }
    if (lane < 8) ea_out[(size_t)n * 8 + q] = acc;
}

// ---- k_mlp1g: zrel(fp16)=[x||ea]@Wz, hroot=relu([x||ea]@Wh+bh) ----
__global__ __launch_bounds__(256) void k_mlp1g(const float* __restrict__ x,
                        const float* __restrict__ ea,
                        const float* __restrict__ Wz, const float* __restrict__ Wh,
                        const float* __restrict__ bh,
                        __half* __restrict__ zrel, float* __restrict__ hroot) {
    __shared__ float As[32][100];    // [node][k], 96 padded to 100
    __shared__ float Ws[96][128];    // [k][j]: j<64 -> Wz, j>=64 -> Wh
    int n0 = blockIdx.x * 32;
    int t = threadIdx.x;
    {   // stage x (cols 0..63)
        int c4 = (t & 15) * 4;
        int r0 = t >> 4;
        #pragma unroll
        for (int r = r0; r < 32; r += 16) {
            int n = min(n0 + r, N - 1);
            *(float4*)&As[r][c4] = *(const float4*)&x[(size_t)n * H + c4];
        }
        // stage ea (cols 64..95)
        int c2 = (t & 7) * 4;
        int r1 = t >> 3;             // 0..31
        int n = min(n0 + r1, N - 1);
        *(float4*)&As[r1][64 + c2] = *(const float4*)&ea[(size_t)n * EC + c2];
    }
    for (int i = t; i < 96 * 128; i += 256) {
        int k = i >> 7, j = i & 127;
        Ws[k][j] = (j < 64) ? Wz[k * 64 + j] : Wh[k * 64 + (j - 64)];
    }
    __syncthreads();
    int tr = t >> 4;                 // rows tr*2 .. tr*2+1
    int tc = t & 15;                 // cols tc*8 .. tc*8+7
    float acc[2][8];
    #pragma unroll
    for (int i = 0; i < 2; ++i)
        #pragma unroll
        for (int j = 0; j < 8; ++j) acc[i][j] = 0.f;
    #pragma unroll 2
    for (int k = 0; k < 96; k += 4) {
        float4 a0 = *(const float4*)&As[tr * 2][k];
        float4 a1 = *(const float4*)&As[tr * 2 + 1][k];
        #pragma unroll
        for (int kk = 0; kk < 4; ++kk) {
            float4 w0 = *(const float4*)&Ws[k + kk][tc * 8];
            float4 w1 = *(const float4*)&Ws[k + kk][tc * 8 + 4];
            float av0 = (kk == 0) ? a0.x : (kk == 1) ? a0.y : (kk == 2) ? a0.z : a0.w;
            float av1 = (kk == 0) ? a1.x : (kk == 1) ? a1.y : (kk == 2) ? a1.z : a1.w;
            acc[0][0] += av0 * w0.x; acc[0][1] += av0 * w0.y;
            acc[0][2] += av0 * w0.z; acc[0][3] += av0 * w0.w;
            acc[0][4] += av0 * w1.x; acc[0][5] += av0 * w1.y;
            acc[0][6] += av0 * w1.z; acc[0][7] += av0 * w1.w;
            acc[1][0] += av1 * w0.x; acc[1][1] += av1 * w0.y;
            acc[1][2] += av1 * w0.z; acc[1][3] += av1 * w0.w;
            acc[1][4] += av1 * w1.x; acc[1][5] += av1 * w1.y;
            acc[1][6] += av1 * w1.z; acc[1][7] += av1 * w1.w;
        }
    }
    if (tc < 8) {                    // zrel cols: pack to fp16, no bias/relu
        int jb = tc * 8;
        #pragma unroll
        for (int i = 0; i < 2; ++i) {
            int n = n0 + tr * 2 + i;
            if (n < N) {
                union { __half2 h[4]; uint4 u; } pk;
                pk.h[0] = __floats2half2_rn(acc[i][0], acc[i][1]);
                pk.h[1] = __floats2half2_rn(acc[i][2], acc[i][3]);
                pk.h[2] = __floats2half2_rn(acc[i][4], acc[i][5]);
                pk.h[3] = __floats2half2_rn(acc[i][6], acc[i][7]);
                *(uint4*)&zrel[(size_t)n * H + jb] = pk.u;
            }
        }
    } else {                         // hroot cols, +bias, relu
        int jb = (tc - 8) * 8;
        float4 b0 = *(const float4*)&bh[jb];
        float4 b1v = *(const float4*)&bh[jb + 4];
        #pragma unroll
        for (int i = 0; i < 2; ++i) {
            int n = n0 + tr * 2 + i;
            if (n < N) {
                *(float4*)&hroot[(size_t)n * H + jb] = make_float4(
                    fmaxf(acc[i][0] + b0.x, 0.f), fmaxf(acc[i][1] + b0.y, 0.f),
                    fmaxf(acc[i][2] + b0.z, 0.f), fmaxf(acc[i][3] + b0.w, 0.f));
                *(float4*)&hroot[(size_t)n * H + jb + 4] = make_float4(
                    fmaxf(acc[i][4] + b1v.x, 0.f), fmaxf(acc[i][5] + b1v.y, 0.f),
                    fmaxf(acc[i][6] + b1v.z, 0.f), fmaxf(acc[i][7] + b1v.w, 0.f));
            }
        }
    }
}

// ---- k_gath: hrel[n] = relu(sum zrel16[src] + relb1); fp16 rows (128 B) ----
// grp=lane>>3 (8 edges/round), q=lane&7 (16B chunk); 4 uint4 loads in flight;
// fp32 accumulate; guarded tail.
__global__ __launch_bounds__(256) void k_gath(const uint4* __restrict__ z16,
                        const unsigned short* __restrict__ srcrow,
                        const int* __restrict__ offC,
                        const float4* __restrict__ relb1_4,
                        float4* __restrict__ hrel4) {
    int n = blockIdx.x * 4 + (threadIdx.x >> 6);
    if (n >= N) return;
    int lane = threadIdx.x & 63;
    int grp = lane >> 3;   // edge subgroup 0..7
    int q   = lane & 7;    // uint4 chunk of the 64-ch fp16 row
    int b = offC[n], e_end = offC[n + 1];
    float av[8];
    #pragma unroll
    for (int c = 0; c < 8; ++c) av[c] = 0.f;
    for (int i0 = b; i0 < e_end; i0 += 32) {
        int lim = e_end - i0;
        int rv = srcrow[min(i0 + lane, e_end - 1)];
        int src[4];
        #pragma unroll
        for (int s = 0; s < 4; ++s) src[s] = __shfl(rv, s * 8 + grp);
        uint4 v[4];
        if (lim >= 32) {
            #pragma unroll
            for (int s = 0; s < 4; ++s) v[s] = z16[(size_t)src[s] * 8 + q];
            #pragma unroll
            for (int s = 0; s < 4; ++s) {
                union { uint4 u; __half2 h[4]; } pk; pk.u = v[s];
                #pragma unroll
                for (int k = 0; k < 4; ++k) {
                    float2 f = __half22float2(pk.h[k]);
                    av[2 * k] += f.x; av[2 * k + 1] += f.y;
                }
            }
        } else {
            #pragma unroll
            for (int s = 0; s < 4; ++s) {
                if (s * 8 + grp < lim) v[s] = z16[(size_t)src[s] * 8 + q];
            }
            #pragma unroll
            for (int s = 0; s < 4; ++s) {
                if (s * 8 + grp < lim) {
                    union { uint4 u; __half2 h[4]; } pk; pk.u = v[s];
                    #pragma unroll
                    for (int k = 0; k < 4; ++k) {
                        float2 f = __half22float2(pk.h[k]);
                        av[2 * k] += f.x; av[2 * k + 1] += f.y;
                    }
                }
            }
        }
    }
    // reduce across the 8 edge-groups (lanes q, q+8, ..., q+56)
    #pragma unroll
    for (int m = 8; m <= 32; m <<= 1) {
        #pragma unroll
        for (int c = 0; c < 8; ++c) av[c] += __shfl_xor(av[c], m);
    }
    if (lane < 8) {
        float4 b1a = relb1_4[q * 2];
        float4 b1b = relb1_4[q * 2 + 1];
        hrel4[(size_t)n * 16 + q * 2] = make_float4(
            fmaxf(av[0] + b1a.x, 0.f), fmaxf(av[1] + b1a.y, 0.f),
            fmaxf(av[2] + b1a.z, 0.f), fmaxf(av[3] + b1a.w, 0.f));
        hrel4[(size_t)n * 16 + q * 2 + 1] = make_float4(
            fmaxf(av[4] + b1b.x, 0.f), fmaxf(av[5] + b1b.y, 0.f),
            fmaxf(av[6] + b1b.z, 0.f), fmaxf(av[7] + b1b.w, 0.f));
    }
}

// ---- k_mlp2g: xout = relu([hrel||hroot](Nx128) @ [Wr;Wo](128x64) + br+bo)
//      dopool: block-segmented pool via reused As LDS (~1 atomic/thread) ----
__global__ __launch_bounds__(256) void k_mlp2g(const float* __restrict__ hrel,
                        const float* __restrict__ hroot,
                        const float* __restrict__ Wr, const float* __restrict__ Wo,
                        const float* __restrict__ br, const float* __restrict__ bo,
                        float* __restrict__ xout,
                        const int* __restrict__ batch, float* __restrict__ pooled,
                        int dopool) {
    __shared__ float As[32][132];    // [node][k]: k<64 hrel, k>=64 hroot (pad)
    __shared__ float Ws[128][64];    // [k][j]: k<64 Wr, k>=64 Wo
    __shared__ int sB[32];
    int n0 = blockIdx.x * 32;
    int t = threadIdx.x;
    {
        int c4 = (t & 15) * 4;
        int r0 = t >> 4;
        #pragma unroll
        for (int r = r0; r < 32; r += 16) {
            int n = min(n0 + r, N - 1);
            *(float4*)&As[r][c4]      = *(const float4*)&hrel [(size_t)n * H + c4];
            *(float4*)&As[r][64 + c4] = *(const float4*)&hroot[(size_t)n * H + c4];
        }
    }
    if (dopool && t < 32) sB[t] = batch[min(n0 + t, N - 1)];
    for (int i = t; i < 128 * 64; i += 256) {
        int k = i >> 6, j = i & 63;
        Ws[k][j] = (k < 64) ? Wr[k * 64 + j] : Wo[(k - 64) * 64 + j];
    }
    __syncthreads();
    int tr = t >> 4;                 // rows tr*2 .. +1
    int tc = t & 15;                 // cols tc*4 .. +3
    float acc[2][4];
    #pragma unroll
    for (int i = 0; i < 2; ++i)
        #pragma unroll
        for (int j = 0; j < 4; ++j) acc[i][j] = 0.f;
    #pragma unroll 2
    for (int k = 0; k < 128; k += 4) {
        float4 a0 = *(const float4*)&As[tr * 2][k];
        float4 a1 = *(const float4*)&As[tr * 2 + 1][k];
        #pragma unroll
        for (int kk = 0; kk < 4; ++kk) {
            float4 w = *(const float4*)&Ws[k + kk][tc * 4];
            float av0 = (kk == 0) ? a0.x : (kk == 1) ? a0.y : (kk == 2) ? a0.z : a0.w;
            float av1 = (kk == 0) ? a1.x : (kk == 1) ? a1.y : (kk == 2) ? a1.z : a1.w;
            acc[0][0] += av0 * w.x; acc[0][1] += av0 * w.y;
            acc[0][2] += av0 * w.z; acc[0][3] += av0 * w.w;
            acc[1][0] += av1 * w.x; acc[1][1] += av1 * w.y;
            acc[1][2] += av1 * w.z; acc[1][3] += av1 * w.w;
        }
    }
    int jb = tc * 4;
    float4 bj;
    bj.x = br[jb]     + bo[jb];
    bj.y = br[jb + 1] + bo[jb + 1];
    bj.z = br[jb + 2] + bo[jb + 2];
    bj.w = br[jb + 3] + bo[jb + 3];
    if (!dopool) {
        #pragma unroll
        for (int i = 0; i < 2; ++i) {
            int n = n0 + tr * 2 + i;
            if (n < N) {
                *(float4*)&xout[(size_t)n * H + jb] = make_float4(
                    fmaxf(acc[i][0] + bj.x, 0.f), fmaxf(acc[i][1] + bj.y, 0.f),
                    fmaxf(acc[i][2] + bj.z, 0.f), fmaxf(acc[i][3] + bj.w, 0.f));
            }
        }
    } else {
        __syncthreads();             // all GEMM reads of As done
        #pragma unroll
        for (int i = 0; i < 2; ++i) {
            int r = tr * 2 + i;
            As[r][jb + 0] = fmaxf(acc[i][0] + bj.x, 0.f);
            As[r][jb + 1] = fmaxf(acc[i][1] + bj.y, 0.f);
            As[r][jb + 2] = fmaxf(acc[i][2] + bj.z, 0.f);
            As[r][jb + 3] = fmaxf(acc[i][3] + bj.w, 0.f);
        }
        __syncthreads();
        // thread t: channel t&63, row group t>>6 (8 rows), segmented by batch
        int ch = t & 63, rg = t >> 6;
        int r0 = rg * 8;
        if (n0 + r0 < N) {
            float a = 0.f;
            int curb = sB[r0];
            for (int r = r0; r < r0 + 8; ++r) {
                int n = n0 + r;
                if (n >= N) break;
                int bb = sB[r];
                if (bb != curb) {
                    atomicAdd(&pooled[(size_t)curb * H + ch], a);
                    a = 0.f; curb = bb;
                }
                a += As[r][ch];
            }
            atomicAdd(&pooled[(size_t)curb * H + ch], a);
        }
    }
}

// ---- out = relu(pooled @ finW1 + finb1) @ finW2 + finb2 ----
__global__ void k_final(const float* __restrict__ pooled,
                        const float* __restrict__ W1, const float* __restrict__ b1,
                        const float* __restrict__ W2, const float* __restrict__ b2,
                        float* __restrict__ out) {
    __shared__ float h[H];
    int g = blockIdx.x;
    int j = threadIdx.x;
    const float* p = pooled + (size_t)g * H;
    float acc = b1[j];
    #pragma unroll 8
    for (int k = 0; k < H; ++k) acc += p[k] * W1[k * H + j];
    h[j] = fmaxf(acc, 0.f);
    __syncthreads();
    if (j < OUTC) {
        float o = b2[j];
        #pragma unroll 8
        for (int k = 0; k < H; ++k) o += h[k] * W2[k * OUTC + j];
        out[(size_t)g * OUTC + j] = o;
    }
}

extern "C" void kernel_launch(void* const* d_in, const int* in_sizes, int n_in,
                              void* d_out, int out_size, void* d_ws, size_t ws_size,
                              hipStream_t stream) {
    const float* x         = (const float*)d_in[0];
    const float* edge_attr = (const float*)d_in[1];
    const float* P[16];
    for (int i = 0; i < 16; ++i) P[i] = (const float*)d_in[2 + i];
    const float* finW1 = (const float*)d_in[18];
    const float* finb1 = (const float*)d_in[19];
    const float* finW2 = (const float*)d_in[20];
    const float* finb2 = (const float*)d_in[21];
    const int* row   = (const int*)d_in[22];
    const int* col   = row + E;
    const int* batch = (const int*)d_in[23];
    float* out = (float*)d_out;
    (void)ws_size; (void)n_in; (void)in_sizes; (void)out_size;

    // ---- workspace ----
    float* fw = (float*)d_ws;
    __half* zrel = (__half*)fw;  fw += (size_t)N * H / 2;   // 6.4MB; aliased by kvR
    float* hroot  = fw;  fw += (size_t)N * H;
    float* x1     = fw;  fw += (size_t)N * H;   // aliased by kvC during build
    float* hrel   = fw;  fw += (size_t)N * H;
    float* ea     = fw;  fw += (size_t)N * EC;
    float* pooled = fw;  fw += (size_t)G * H;
    int* iw = (int*)fw;
    int* cntR   = iw;  iw += NB;
    int* cntC   = iw;  iw += NB;
    int* baseR  = iw;  iw += NB;
    int* baseC  = iw;  iw += NB;
    int* curR   = iw;  iw += NB;
    int* curC   = iw;  iw += NB;
    int* offR   = iw;  iw += N + 1;
    int* offC   = iw;  iw += N + 1;
    int* eid    = iw;  iw += E;
    unsigned short* srcrow = (unsigned short*)iw;  iw += E / 2;
    int* bhR    = iw;  iw += P1G * NB;
    int* bhC    = iw;  iw += P1G * NB;
    // 4B kv arrays alias node float arrays (build-only lifetime)
    unsigned* kvR = (unsigned*)zrel;   // E*4B = 6.4MB == zrel_fp16 region
    unsigned* kvC = (unsigned*)x1;

    // ---- build CSR/CSC ----
    hipMemsetAsync(cntR, 0, 2 * (size_t)NB * sizeof(int), stream);
    hipMemsetAsync(pooled, 0, (size_t)G * H * sizeof(float), stream);
    k_p1hist<<<P1G, 256, 0, stream>>>(row, col, cntR, cntC, bhR, bhC);
    k_bscan<<<1, 256, 0, stream>>>(cntR, cntC, baseR, baseC, curR, curC, offR, offC);
    k_p1scat<<<P1G, 256, 0, stream>>>(row, col, bhR, bhC, curR, curC, kvR, kvC);
    k_p2<<<2 * NB, 256, 0, stream>>>(kvR, kvC, baseR, baseC, cntR, cntC,
                                     offR, offC, eid, srcrow);

    // ---- shared edge aggregation ----
    k_ea_gather<<<(N + 3) / 4, 256, 0, stream>>>((const float4*)edge_attr, eid, offR,
                                                 (float4*)ea);

    int gmlp = (N + 31) / 32;   // 1563

    // ---- layer 1 ----
    k_mlp1g<<<gmlp, 256, 0, stream>>>(x, ea, P[0], P[4], P[5], zrel, hroot);
    k_gath<<<(N + 3) / 4, 256, 0, stream>>>((const uint4*)zrel, srcrow, offC,
                                            (const float4*)P[1], (float4*)hrel);
    k_mlp2g<<<gmlp, 256, 0, stream>>>(hrel, hroot, P[2], P[6], P[3], P[7], x1,
                                      batch, pooled, 0);

    // ---- layer 2 (mlp2 + pool fused, block-segmented) ----
    k_mlp1g<<<gmlp, 256, 0, stream>>>(x1, ea, P[8], P[12], P[13], zrel, hroot);
    k_gath<<<(N + 3) / 4, 256, 0, stream>>>((const uint4*)zrel, srcrow, offC,
                                            (const float4*)P[9], (float4*)hrel);
    k_mlp2g<<<gmlp, 256, 0, stream>>>(hrel, hroot, P[10], P[14], P[11], P[15], x1,
                                      batch, pooled, 1);

    // ---- head ----
    k_final<<<G, 64, 0, stream>>>(pooled, finW1, finb1, finW2, finb2, out);
}